// Round 17
// baseline (4418.184 us; speedup 1.0000x reference)
//
#include <hip/hip_runtime.h>
#include <math.h>

#define NB 128
#define NP 196
#define NENC 2048
#define NE 512
#define ND 512
#define NA 512
#define NV 10000
#define NVPAD 10112
#define NL 52
#define NT 51
#define KXH2 2560   // [attw 2048 | h 512]

typedef unsigned short u16;
typedef unsigned char u8;
typedef __attribute__((ext_vector_type(8))) short bf16x8;
typedef __attribute__((ext_vector_type(8))) unsigned short u16x8;
typedef __attribute__((ext_vector_type(4))) float f32x4;

#define MFMA16 __builtin_amdgcn_mfma_f32_16x16x32_bf16

__device__ __forceinline__ float sigmoidf_(float v) { return 1.0f / (1.0f + __expf(-v)); }
__device__ __forceinline__ float b2f(u16 u) { return __uint_as_float(((unsigned int)u) << 16); }
__device__ __forceinline__ u16 f2b(float f) {
  unsigned int u = __float_as_uint(f);
  unsigned int r = (u + 0x7FFFu + ((u >> 16) & 1u)) >> 16;
  return (u16)r;
}

// ---- fp8 e4m3 (OCP) helpers; SEL must be compile-time constant ----
template <int SEL>
__device__ __forceinline__ float fp8tof(unsigned int data) {
#if __has_builtin(__builtin_amdgcn_cvt_f32_fp8)
  return __builtin_amdgcn_cvt_f32_fp8(data, SEL);
#else
  unsigned int b = (data >> (SEL * 8)) & 0xFFu;
  unsigned int s = (b & 0x80u) << 24;
  unsigned int em = b & 0x7Fu;
  float mag;
  if ((em >> 3) == 0) mag = (float)em * 0.001953125f;   // denormal: em * 2^-9
  else mag = __uint_as_float((((em >> 3) + 120) << 23) | ((em & 7u) << 20));
  return __uint_as_float(s | __float_as_uint(mag));
#endif
}
__device__ __forceinline__ u8 ftofp8(float f) {
  unsigned int u = __float_as_uint(f);
  unsigned int s = (u >> 24) & 0x80u;
  float af = fabsf(f);
  if (af >= 448.0f) return (u8)(s | 0x7Eu);
  if (af < 0.015625f) {                       // denormal range
    int m = (int)(af * 512.0f + 0.5f);
    if (m >= 8) return (u8)(s | 0x08u);
    return (u8)(s | (unsigned int)m);
  }
  int e = (int)((u >> 23) & 0xFF) - 127;
  unsigned int m3 = (u >> 20) & 7u;
  unsigned int rest = u & 0xFFFFFu;
  if (rest > 0x80000u || (rest == 0x80000u && (m3 & 1u))) { m3++; if (m3 == 8u) { m3 = 0u; e++; } }
  if (e > 8) return (u8)(s | 0x7Eu);
  return (u8)(s | ((unsigned int)(e + 7) << 3) | m3);
}

// ---------------- sort + nact + dlen_sorted ----------------
__global__ void kSort(const int* __restrict__ cap_len, const int* __restrict__ captions,
                      int* __restrict__ order, int* __restrict__ nact,
                      int* __restrict__ dlen_sorted,
                      float* __restrict__ out_cap, float* __restrict__ out_dlen) {
  __shared__ int lens[NB];
  __shared__ int s_dl[NB];
  int tid = threadIdx.x;
  lens[tid] = cap_len[tid];
  __syncthreads();
  int li = lens[tid];
  int r = 0;
  for (int j = 0; j < NB; ++j) {
    int lj = lens[j];
    if (lj > li || (lj == li && j < tid)) r++;
  }
  order[r] = tid;
  s_dl[r] = li - 1;
  dlen_sorted[r] = li - 1;
  out_dlen[r] = (float)(li - 1);
  for (int l = 0; l < NL; ++l)
    out_cap[(size_t)r * NL + l] = (float)captions[(size_t)tid * NL + l];
  __syncthreads();
  if (tid < NT) {
    int cnt = 0;
    for (int j = 0; j < NB; ++j) cnt += (s_dl[j] > tid) ? 1 : 0;
    nact[tid] = cnt;
  }
}

__global__ void kAlphaZero(const int* __restrict__ nact, float* __restrict__ out_alph) {
  int t = blockIdx.x;
  int n0 = nact[t];
  int cnt = (NB - n0) * NP;
  for (int i = threadIdx.x; i < cnt; i += 256) {
    int b = n0 + i / NP;
    int p = i - (i / NP) * NP;
    out_alph[((size_t)b * NT + t) * NP + p] = 0.0f;
  }
}

// ---------------- zero the per-row tail of predictions ----------------
__global__ __launch_bounds__(256) void kPredTail(const int* __restrict__ dlen_sorted,
                                                 float* __restrict__ out_pred) {
  int row = blockIdx.x;
  int d = dlen_sorted[row];
  int cnt = (NT - d) * NV;
  float* base = out_pred + (size_t)row * NT * NV + (size_t)d * NV;
  f32x4 z = {0.0f, 0.0f, 0.0f, 0.0f};
  int start = (blockIdx.y * 256 + threadIdx.x) * 4;
  int step = gridDim.y * 256 * 4;
  for (int i = start; i < cnt; i += step)
    *(f32x4*)&base[i] = z;
}

// ---------------- features gather + bf16 + fp8 ----------------
__global__ void kFeats(const float* __restrict__ features, const int* __restrict__ order,
                       u16* __restrict__ featsb, u8* __restrict__ featsb8) {
  int p = blockIdx.x, b = blockIdx.y, tid = threadIdx.x;
  const float* src = features + ((size_t)order[b] * NP + p) * NENC + tid * 8;
  float4 v0 = *(const float4*)src;
  float4 v1 = *(const float4*)(src + 4);
  u16x8 o;
  o[0] = f2b(v0.x); o[1] = f2b(v0.y); o[2] = f2b(v0.z); o[3] = f2b(v0.w);
  o[4] = f2b(v1.x); o[5] = f2b(v1.y); o[6] = f2b(v1.z); o[7] = f2b(v1.w);
  *(u16x8*)(featsb + ((size_t)b * NP + p) * NENC + tid * 8) = o;
  uint2 q;
  q.x = (unsigned int)ftofp8(v0.x) | ((unsigned int)ftofp8(v0.y) << 8) |
        ((unsigned int)ftofp8(v0.z) << 16) | ((unsigned int)ftofp8(v0.w) << 24);
  q.y = (unsigned int)ftofp8(v1.x) | ((unsigned int)ftofp8(v1.y) << 8) |
        ((unsigned int)ftofp8(v1.z) << 16) | ((unsigned int)ftofp8(v1.w) << 24);
  *(uint2*)(featsb8 + ((size_t)b * NP + p) * NENC + tid * 8) = q;
}

// ---------------- unified LDS-tiled transpose ----------------
__device__ __forceinline__ float tfetch(int mode, int k, int n,
                                        const float* __restrict__ A,
                                        const float* __restrict__ B) {
  switch (mode) {
    case 0: return A[(size_t)k * NA + n];
    case 1: return (n < NA) ? A[(size_t)k * NA + n] : B[(size_t)k * NENC + (n - NA)];
    case 2: return A[(size_t)k * (4 * ND) + (n & 3) * ND + (n >> 2)];
    case 3: {
      int col = (n & 3) * ND + (n >> 2);
      return (k < NENC) ? A[(size_t)(NE + k) * (4 * ND) + col]
                        : B[(size_t)(k - NENC) * (4 * ND) + col];
    }
    case 4: return (n < NV) ? A[(size_t)k * NV + n] : 0.0f;
    default: return (n < NA) ? A[(size_t)k * ND + n] : B[(size_t)k * ND + (n - NA)];
  }
}

__global__ __launch_bounds__(256) void kTrans(const float* __restrict__ A,
                                              const float* __restrict__ B,
                                              u16* __restrict__ dst,
                                              int K, int N, int mode) {
  __shared__ u16 T[32][136];
  int n0 = blockIdx.x * 32, k0 = blockIdx.y * 128;
  int tid = threadIdx.x;
  int c = tid & 31, kr = tid >> 5;
#pragma unroll
  for (int pass = 0; pass < 16; ++pass) {
    int kl = pass * 8 + kr;
    T[c][kl] = f2b(tfetch(mode, k0 + kl, n0 + c, A, B));
  }
  __syncthreads();
  int row = tid >> 3, seg = tid & 7;
  u16x8 v0, v1;
#pragma unroll
  for (int j = 0; j < 8; ++j) { v0[j] = T[row][seg * 16 + j]; v1[j] = T[row][seg * 16 + 8 + j]; }
  *(u16x8*)&dst[(size_t)(n0 + row) * K + k0 + seg * 16] = v0;
  *(u16x8*)&dst[(size_t)(n0 + row) * K + k0 + seg * 16 + 8] = v1;
}

// ---------------- embA gather ----------------
__global__ void kEmbA(const float* __restrict__ emb, const int* __restrict__ captions,
                      const int* __restrict__ order, u16* __restrict__ embA) {
  int t = blockIdx.x, b = blockIdx.y;
  int tok = captions[(size_t)order[b] * NL + t];
  int i = threadIdx.x * 2;
  float2 v = *(const float2*)(emb + (size_t)tok * NE + i);
  unsigned int w0 = (unsigned int)f2b(v.x) | ((unsigned int)f2b(v.y) << 16);
  *(unsigned int*)(embA + ((size_t)t * NB + b) * NE + i) = w0;
}

// ---------------- embAll = embA @ WihTopT ----------------
__global__ __launch_bounds__(256) void kEmbGemm(const u16* __restrict__ A,
                                                const u16* __restrict__ BT,
                                                u16* __restrict__ D) {
  int w = threadIdx.x >> 6, lane = threadIdx.x & 63;
  int lr = lane & 15, lg = lane >> 4;
  int mb = blockIdx.y * 128 + w * 32;
  int nb = blockIdx.x * 64;
  f32x4 acc[2][4] = {};
  const u16* a0 = A + (size_t)(mb + lr) * NE + lg * 8;
  const u16* a1 = a0 + 16 * NE;
  const u16* b0 = BT + (size_t)(nb + lr) * NE + lg * 8;
  for (int k0 = 0; k0 < NE; k0 += 32) {
    bf16x8 af0 = *(const bf16x8*)(a0 + k0);
    bf16x8 af1 = *(const bf16x8*)(a1 + k0);
#pragma unroll
    for (int nt = 0; nt < 4; ++nt) {
      bf16x8 bf = *(const bf16x8*)(b0 + (size_t)nt * 16 * NE + k0);
      acc[0][nt] = MFMA16(af0, bf, acc[0][nt], 0, 0, 0);
      acc[1][nt] = MFMA16(af1, bf, acc[1][nt], 0, 0, 0);
    }
  }
#pragma unroll
  for (int mt = 0; mt < 2; ++mt)
#pragma unroll
    for (int nt = 0; nt < 4; ++nt)
#pragma unroll
      for (int j = 0; j < 4; ++j) {
        int row = mb + mt * 16 + lg * 4 + j;
        int col = nb + nt * 16 + lr;
        D[(size_t)row * NENC + col] = f2b(acc[mt][nt][j]);
      }
}

// ---------------- eo = mean over P ----------------
__global__ void kEo(const u16* __restrict__ featsb, u16* __restrict__ eob) {
  int e = blockIdx.x * 256 + threadIdx.x;
  int b = blockIdx.y;
  const u16* f = featsb + (size_t)b * NP * NENC + e;
  float s = 0.0f;
  for (int p = 0; p < NP; ++p) s += b2f(f[(size_t)p * NENC]);
  eob[(size_t)b * NENC + e] = f2b(s * (1.0f / NP));
}

// ---------------- h0/c0 via MFMA ----------------
__global__ __launch_bounds__(64) void kHC0(const u16* __restrict__ eob,
                                           const u16* __restrict__ BT,
                                           const float* __restrict__ b_h0,
                                           const float* __restrict__ b_c0,
                                           u16* __restrict__ hb, u16* __restrict__ xh0,
                                           float* __restrict__ c) {
  int lane = threadIdx.x;
  int lr = lane & 15, lg = lane >> 4;
  int mb = blockIdx.y * 32, nb = blockIdx.x * 32;
  f32x4 acc[2][2] = {};
  const u16* a0 = eob + (size_t)(mb + lr) * NENC + lg * 8;
  const u16* a1 = a0 + 16 * NENC;
  const u16* b0 = BT + (size_t)(nb + lr) * NENC + lg * 8;
  const u16* b1 = b0 + 16 * NENC;
#pragma unroll 4
  for (int k0 = 0; k0 < NENC; k0 += 32) {
    bf16x8 af0 = *(const bf16x8*)(a0 + k0);
    bf16x8 af1 = *(const bf16x8*)(a1 + k0);
    bf16x8 bv0 = *(const bf16x8*)(b0 + k0);
    bf16x8 bv1 = *(const bf16x8*)(b1 + k0);
    acc[0][0] = MFMA16(af0, bv0, acc[0][0], 0, 0, 0);
    acc[1][0] = MFMA16(af1, bv0, acc[1][0], 0, 0, 0);
    acc[0][1] = MFMA16(af0, bv1, acc[0][1], 0, 0, 0);
    acc[1][1] = MFMA16(af1, bv1, acc[1][1], 0, 0, 0);
  }
#pragma unroll
  for (int mt = 0; mt < 2; ++mt)
#pragma unroll
    for (int nt = 0; nt < 2; ++nt)
#pragma unroll
      for (int j = 0; j < 4; ++j) {
        int row = mb + mt * 16 + lg * 4 + j;
        int n = nb + nt * 16 + lr;
        if (n < NA) {
          u16 hv = f2b(acc[mt][nt][j] + b_h0[n]);
          hb[(size_t)row * ND + n] = hv;
          xh0[(size_t)row * KXH2 + NENC + n] = hv;
        } else {
          c[(size_t)row * ND + (n - NA)] = acc[mt][nt][j] + b_c0[n - NA];
        }
      }
}

// ---------------- enc_proj: 128x64 tiles, dbuf LDS A, XCD swizzle ----------------
__global__ __launch_bounds__(256) void kEncProj(const u16* __restrict__ A,
                                                const u16* __restrict__ BT,
                                                const float* __restrict__ bias,
                                                u16* __restrict__ D) {
  __shared__ u16 As[2][128][72];
  int lin = ((int)blockIdx.x % 8) * 196 + (int)blockIdx.x / 8;  // 1568 = 8*196
  int mt = lin >> 3, ntile = lin & 7;
  int mb = mt * 128, nb = ntile * 64;
  int tid = threadIdx.x;
  int w = tid >> 6, lane = tid & 63;
  int lr = lane & 15, lg = lane >> 4;

  int arow[4], akp[4];
  const u16* aptr[4];
#pragma unroll
  for (int i = 0; i < 4; ++i) {
    int idx = i * 256 + tid;
    arow[i] = idx >> 3;
    akp[i] = idx & 7;
    aptr[i] = A + (size_t)(mb + arow[i]) * NENC + akp[i] * 8;
  }
  u16x8 s0 = *(const u16x8*)(aptr[0]);
  u16x8 s1 = *(const u16x8*)(aptr[1]);
  u16x8 s2 = *(const u16x8*)(aptr[2]);
  u16x8 s3 = *(const u16x8*)(aptr[3]);
  *(u16x8*)&As[0][arow[0]][akp[0] * 8] = s0;
  *(u16x8*)&As[0][arow[1]][akp[1] * 8] = s1;
  *(u16x8*)&As[0][arow[2]][akp[2] * 8] = s2;
  *(u16x8*)&As[0][arow[3]][akp[3] * 8] = s3;

  f32x4 acc[2][4] = {};
  const u16* bbase = BT + (size_t)(nb + lr) * NENC + lg * 8;
  int cur = 0;
  int r0 = w * 32 + lr;

  for (int k0 = 0; k0 < NENC; k0 += 64) {
    __syncthreads();
    bool more = (k0 + 64 < NENC);
    if (more) {
      s0 = *(const u16x8*)(aptr[0] + k0 + 64);
      s1 = *(const u16x8*)(aptr[1] + k0 + 64);
      s2 = *(const u16x8*)(aptr[2] + k0 + 64);
      s3 = *(const u16x8*)(aptr[3] + k0 + 64);
    }
#pragma unroll
    for (int kh = 0; kh < 2; ++kh) {
      bf16x8 af0 = *(const bf16x8*)&As[cur][r0][kh * 32 + lg * 8];
      bf16x8 af1 = *(const bf16x8*)&As[cur][r0 + 16][kh * 32 + lg * 8];
#pragma unroll
      for (int nt = 0; nt < 4; ++nt) {
        bf16x8 bf = *(const bf16x8*)(bbase + (size_t)nt * 16 * NENC + k0 + kh * 32);
        acc[0][nt] = MFMA16(af0, bf, acc[0][nt], 0, 0, 0);
        acc[1][nt] = MFMA16(af1, bf, acc[1][nt], 0, 0, 0);
      }
    }
    if (more) {
      *(u16x8*)&As[cur ^ 1][arow[0]][akp[0] * 8] = s0;
      *(u16x8*)&As[cur ^ 1][arow[1]][akp[1] * 8] = s1;
      *(u16x8*)&As[cur ^ 1][arow[2]][akp[2] * 8] = s2;
      *(u16x8*)&As[cur ^ 1][arow[3]][akp[3] * 8] = s3;
    }
    cur ^= 1;
  }
  __syncthreads();
  u16* eps = (u16*)As;             // [128][72]
#pragma unroll
  for (int m2 = 0; m2 < 2; ++m2)
#pragma unroll
    for (int nt = 0; nt < 4; ++nt)
#pragma unroll
      for (int j = 0; j < 4; ++j) {
        int rloc = w * 32 + m2 * 16 + lg * 4 + j;
        int col = nt * 16 + lr;
        eps[rloc * 72 + col] = f2b(acc[m2][nt][j] + bias[nb + col]);
      }
  __syncthreads();
#pragma unroll
  for (int i = 0; i < 4; ++i) {
    int idx = i * 256 + tid;
    int row = idx >> 3, seg = idx & 7;
    *(u16x8*)&D[(size_t)(mb + row) * NA + nb + seg * 8] = *(u16x8*)&eps[row * 72 + seg * 8];
  }
}

// ---------------- kDecGate: 1D grid 320, XCD-chunked ----------------
__global__ __launch_bounds__(64) void kDecGate(const u16* __restrict__ hb,
                                               const u16* __restrict__ BT,
                                               const float* __restrict__ b_dec,
                                               const float* __restrict__ b_beta,
                                               const int* __restrict__ nact, int t,
                                               float* __restrict__ dec_proj,
                                               float* __restrict__ gate_raw) {
  int nact_t = nact[t];
  int lin = ((int)blockIdx.x % 8) * 40 + (int)blockIdx.x / 8;   // 320 = 8*40
  int mb = (lin & 3) * 32;
  if (mb >= nact_t) return;
  int nb = (lin >> 2) * 32;
  int lane = threadIdx.x;
  int lr = lane & 15, lg = lane >> 4;
  f32x4 acc[2][2] = {};
  const u16* a0 = hb + (size_t)(mb + lr) * ND + lg * 8;
  const u16* a1 = a0 + 16 * ND;
  const u16* b0 = BT + (size_t)(nb + lr) * ND + lg * 8;
  const u16* b1 = b0 + 16 * ND;
#pragma unroll 4
  for (int k0 = 0; k0 < ND; k0 += 32) {
    bf16x8 af0 = *(const bf16x8*)(a0 + k0);
    bf16x8 af1 = *(const bf16x8*)(a1 + k0);
    bf16x8 bv0 = *(const bf16x8*)(b0 + k0);
    bf16x8 bv1 = *(const bf16x8*)(b1 + k0);
    acc[0][0] = MFMA16(af0, bv0, acc[0][0], 0, 0, 0);
    acc[1][0] = MFMA16(af1, bv0, acc[1][0], 0, 0, 0);
    acc[0][1] = MFMA16(af0, bv1, acc[0][1], 0, 0, 0);
    acc[1][1] = MFMA16(af1, bv1, acc[1][1], 0, 0, 0);
  }
#pragma unroll
  for (int mt = 0; mt < 2; ++mt)
#pragma unroll
    for (int nt = 0; nt < 2; ++nt)
#pragma unroll
      for (int j = 0; j < 4; ++j) {
        int row = mb + mt * 16 + lg * 4 + j;
        int n = nb + nt * 16 + lr;
        if (n < NA)
          dec_proj[(size_t)row * NA + n] = acc[mt][nt][j] + b_dec[n];
        else
          gate_raw[(size_t)row * NENC + (n - NA)] = acc[mt][nt][j] + b_beta[n - NA];
      }
}

// ---------------- kSAX: one block per b; scores once + fp8 attw (4 cols/thr) ----------------
__global__ __launch_bounds__(512) void kSAX(const u8* __restrict__ featsb8,
                                            const u16* __restrict__ encb,
                                            const float* __restrict__ dec_proj,
                                            const float* __restrict__ gate_raw,
                                            const float* __restrict__ w_full,
                                            const float* __restrict__ b_full,
                                            const int* __restrict__ nact, int t,
                                            u16* __restrict__ xh_w,
                                            float* __restrict__ out_alph) {
  int b = blockIdx.x, tid = threadIdx.x;
  if (b >= nact[t]) return;
  __shared__ float s_dp[NA], s_wf[NA], s_al[NP + 12], red[16];
  if (tid < NA) { s_dp[tid] = dec_proj[(size_t)b * NA + tid]; s_wf[tid] = w_full[tid]; }
  __syncthreads();
  int wave = tid >> 6, lane = tid & 63;
  float bf_ = b_full[0];
  for (int p = wave; p < NP; p += 8) {
    const u16* ep = encb + ((size_t)b * NP + p) * NA + lane * 8;
    u16x8 v = *(const u16x8*)ep;
    float acc = 0.0f;
#pragma unroll
    for (int j = 0; j < 8; ++j) {
      int a = lane * 8 + j;
      float vv = b2f(v[j]) + s_dp[a];
      acc += fmaxf(vv, 0.0f) * s_wf[a];
    }
#pragma unroll
    for (int off = 32; off; off >>= 1) acc += __shfl_down(acc, off);
    if (lane == 0) s_al[p] = acc + bf_;
  }
  __syncthreads();
  float mx = (tid < NP) ? s_al[tid] : -3.4e38f;
#pragma unroll
  for (int off = 32; off; off >>= 1) mx = fmaxf(mx, __shfl_down(mx, off));
  if (lane == 0) red[wave] = mx;
  __syncthreads();
  if (tid == 0) {
    float m = red[0];
    for (int i = 1; i < 8; ++i) m = fmaxf(m, red[i]);
    red[0] = m;
  }
  __syncthreads();
  float m2v = red[0];
  float e = 0.0f;
  if (tid < NP) { e = __expf(s_al[tid] - m2v); s_al[tid] = e; }
#pragma unroll
  for (int off = 32; off; off >>= 1) e += __shfl_down(e, off);
  if (lane == 0) red[8 + wave] = e;
  __syncthreads();
  if (tid == 0) {
    float s = 0.0f;
    for (int i = 0; i < 8; ++i) s += red[8 + i];
    red[8] = 1.0f / s;
  }
  __syncthreads();
  float inv = red[8];
  if (tid < NP) {
    float al = s_al[tid] * inv;
    s_al[tid] = al;
    out_alph[((size_t)b * NT + t) * NP + tid] = al;
  }
  __syncthreads();
  // attw: 4 cols per thread from fp8 features
  int e0 = tid * 4;
  float ac0 = 0.0f, ac1 = 0.0f, ac2 = 0.0f, ac3 = 0.0f;
  const u8* fb = featsb8 + (size_t)b * NP * NENC + e0;
#pragma unroll 2
  for (int p = 0; p < NP; ++p) {
    unsigned int v = *(const unsigned int*)(fb + (size_t)p * NENC);
    float al = s_al[p];
    ac0 += al * fp8tof<0>(v);
    ac1 += al * fp8tof<1>(v);
    ac2 += al * fp8tof<2>(v);
    ac3 += al * fp8tof<3>(v);
  }
  const float* gr = gate_raw + (size_t)b * NENC + e0;
  unsigned int lo = (unsigned int)f2b(ac0 * sigmoidf_(gr[0])) |
                    ((unsigned int)f2b(ac1 * sigmoidf_(gr[1])) << 16);
  unsigned int hi = (unsigned int)f2b(ac2 * sigmoidf_(gr[2])) |
                    ((unsigned int)f2b(ac3 * sigmoidf_(gr[3])) << 16);
  uint2 o; o.x = lo; o.y = hi;
  *(uint2*)(xh_w + (size_t)b * KXH2 + e0) = o;
}

// ---------------- kGatesLstm: 32x32 tile/block, 8-way K-split, XCD-chunked ----------------
__global__ __launch_bounds__(1024) void kGatesLstm(const u16* __restrict__ xh_r,
                                                   const u16* __restrict__ WifgoT2,
                                                   const u16* __restrict__ embAll,
                                                   const float* __restrict__ b_ih,
                                                   const float* __restrict__ b_hh,
                                                   const int* __restrict__ nact, int t,
                                                   float* __restrict__ cst,
                                                   u16* __restrict__ hb,
                                                   u16* __restrict__ hnewAll_t,
                                                   u16* __restrict__ xh_w) {
  __shared__ float smem[8 * 32 * 33];
  int nact_t = nact[t];
  int tid = threadIdx.x;
  int w = tid >> 6, lane = tid & 63;
  int lr = lane & 15, lg = lane >> 4;
  int lin = ((int)blockIdx.x % 8) * 32 + (int)blockIdx.x / 8;   // 256 = 8*32
  int rt = lin & 3, ct = lin >> 2;
  int mb = rt * 32, nb = ct * 32;
  int kq = w >> 1, mh = w & 1;
  if (mb < nact_t) {
    f32x4 acc0 = {}, acc1 = {};
    const u16* pa = xh_r + (size_t)(mb + mh * 16 + lr) * KXH2 + kq * 320 + lg * 8;
    const u16* pb0 = WifgoT2 + (size_t)(nb + lr) * KXH2 + kq * 320 + lg * 8;
    const u16* pb1 = pb0 + (size_t)16 * KXH2;
#pragma unroll
    for (int k0 = 0; k0 < 320; k0 += 32) {
      bf16x8 af = *(const bf16x8*)(pa + k0);
      bf16x8 bv0 = *(const bf16x8*)(pb0 + k0);
      bf16x8 bv1 = *(const bf16x8*)(pb1 + k0);
      acc0 = MFMA16(af, bv0, acc0, 0, 0, 0);
      acc1 = MFMA16(af, bv1, acc1, 0, 0, 0);
    }
#pragma unroll
    for (int j = 0; j < 4; ++j) {
      int rr = kq * 32 + mh * 16 + lg * 4 + j;
      smem[rr * 33 + lr] = acc0[j];
      smem[rr * 33 + 16 + lr] = acc1[j];
    }
  }
  __syncthreads();
  if (tid < 256) {
    int row = tid >> 3, dl = tid & 7;
    int grow = mb + row;
    int d = ct * 8 + dl;
    size_t off = (size_t)grow * ND + d;
    if (grow < nact_t) {
      float g4[4];
#pragma unroll
      for (int g = 0; g < 4; ++g) {
        int col = dl * 4 + g;
        float s = 0.0f;
#pragma unroll
        for (int q = 0; q < 8; ++q) s += smem[(q * 32 + row) * 33 + col];
        s += b2f(embAll[((size_t)t * NB + grow) * NENC + nb + col]);
        g4[g] = s;
      }
      float gi = g4[0] + b_ih[d] + b_hh[d];
      float gf = g4[1] + b_ih[ND + d] + b_hh[ND + d];
      float gg = g4[2] + b_ih[2 * ND + d] + b_hh[2 * ND + d];
      float go = g4[3] + b_ih[3 * ND + d] + b_hh[3 * ND + d];
      float cn = sigmoidf_(gf) * cst[off] + sigmoidf_(gi) * tanhf(gg);
      float hn = sigmoidf_(go) * tanhf(cn);
      u16 hv = f2b(hn);
      cst[off] = cn;
      hb[off] = hv;
      hnewAll_t[off] = hv;
      xh_w[(size_t)grow * KXH2 + NENC + d] = hv;
    } else {
      xh_w[(size_t)grow * KXH2 + NENC + d] = hb[off];
    }
  }
}

// ---------------- preds GEMM: t-paired blocks (B reuse x2), XCD-chunked ----------------
__global__ __launch_bounds__(256) void kPredsAll6(const u16* __restrict__ hnewAll,
                                                  const u16* __restrict__ BT,
                                                  const float* __restrict__ b_fc,
                                                  const int* __restrict__ nact,
                                                  float* __restrict__ out_pred) {
  __shared__ float ts[128][68];
  int lin = ((int)blockIdx.x & 7) * 520 + ((int)blockIdx.x >> 3);
  if (lin >= 158 * 26) return;
  int nbi = lin / 26;
  int tp = lin - nbi * 26;
  int t0 = tp * 2;
  int t1 = t0 + 1;
  bool has1 = (t1 < NT);
  int nb = nbi * 64;
  int nact0 = nact[t0];
  int nact1 = has1 ? nact[t1] : 0;
  int w = threadIdx.x >> 6, lane = threadIdx.x & 63;
  int lr = lane & 15, lg = lane >> 4;
  int mb = w * 32;
  f32x4 acc0[2][4] = {};
  f32x4 acc1[2][4] = {};
  bool do1 = has1 && (mb < nact1);
  if (mb < nact0) {
    const u16* a0 = hnewAll + (size_t)t0 * NB * ND + (size_t)(mb + lr) * ND + lg * 8;
    const u16* a1 = a0 + 16 * ND;
    const u16* a0b = a0 + (size_t)NB * ND;
    const u16* a1b = a1 + (size_t)NB * ND;
    const u16* b0 = BT + (size_t)(nb + lr) * ND + lg * 8;
    for (int k0 = 0; k0 < ND; k0 += 32) {
      bf16x8 bf0 = *(const bf16x8*)(b0 + k0);
      bf16x8 bf1 = *(const bf16x8*)(b0 + (size_t)16 * ND + k0);
      bf16x8 bf2 = *(const bf16x8*)(b0 + (size_t)32 * ND + k0);
      bf16x8 bf3 = *(const bf16x8*)(b0 + (size_t)48 * ND + k0);
      bf16x8 af0 = *(const bf16x8*)(a0 + k0);
      bf16x8 af1 = *(const bf16x8*)(a1 + k0);
      acc0[0][0] = MFMA16(af0, bf0, acc0[0][0], 0, 0, 0);
      acc0[1][0] = MFMA16(af1, bf0, acc0[1][0], 0, 0, 0);
      acc0[0][1] = MFMA16(af0, bf1, acc0[0][1], 0, 0, 0);
      acc0[1][1] = MFMA16(af1, bf1, acc0[1][1], 0, 0, 0);
      acc0[0][2] = MFMA16(af0, bf2, acc0[0][2], 0, 0, 0);
      acc0[1][2] = MFMA16(af1, bf2, acc0[1][2], 0, 0, 0);
      acc0[0][3] = MFMA16(af0, bf3, acc0[0][3], 0, 0, 0);
      acc0[1][3] = MFMA16(af1, bf3, acc0[1][3], 0, 0, 0);
      if (do1) {
        bf16x8 ag0 = *(const bf16x8*)(a0b + k0);
        bf16x8 ag1 = *(const bf16x8*)(a1b + k0);
        acc1[0][0] = MFMA16(ag0, bf0, acc1[0][0], 0, 0, 0);
        acc1[1][0] = MFMA16(ag1, bf0, acc1[1][0], 0, 0, 0);
        acc1[0][1] = MFMA16(ag0, bf1, acc1[0][1], 0, 0, 0);
        acc1[1][1] = MFMA16(ag1, bf1, acc1[1][1], 0, 0, 0);
        acc1[0][2] = MFMA16(ag0, bf2, acc1[0][2], 0, 0, 0);
        acc1[1][2] = MFMA16(ag1, bf2, acc1[1][2], 0, 0, 0);
        acc1[0][3] = MFMA16(ag0, bf3, acc1[0][3], 0, 0, 0);
        acc1[1][3] = MFMA16(ag1, bf3, acc1[1][3], 0, 0, 0);
      }
    }
  }
  int tid = threadIdx.x;
#pragma unroll
  for (int mt = 0; mt < 2; ++mt)
#pragma unroll
    for (int nt = 0; nt < 4; ++nt)
#pragma unroll
      for (int j = 0; j < 4; ++j) {
        int row = mb + mt * 16 + lg * 4 + j;
        int gn = nb + nt * 16 + lr;
        float bias = (gn < NV) ? b_fc[gn] : 0.0f;
        ts[row][nt * 16 + lr] = acc0[mt][nt][j] + bias;
      }
  __syncthreads();
#pragma unroll
  for (int i = 0; i < 8; ++i) {
    int idx = i * 256 + tid;
    int row = idx >> 4;
    int c4 = (idx & 15) * 4;
    int gn = nb + c4;
    if (row < nact0 && gn < NV) {
      f32x4 v = *(const f32x4*)&ts[row][c4];
      *(f32x4*)&out_pred[((size_t)row * NT + t0) * NV + gn] = v;
    }
  }
  if (!has1) return;
  __syncthreads();
#pragma unroll
  for (int mt = 0; mt < 2; ++mt)
#pragma unroll
    for (int nt = 0; nt < 4; ++nt)
#pragma unroll
      for (int j = 0; j < 4; ++j) {
        int row = mb + mt * 16 + lg * 4 + j;
        int gn = nb + nt * 16 + lr;
        float bias = (gn < NV) ? b_fc[gn] : 0.0f;
        ts[row][nt * 16 + lr] = acc1[mt][nt][j] + bias;
      }
  __syncthreads();
#pragma unroll
  for (int i = 0; i < 8; ++i) {
    int idx = i * 256 + tid;
    int row = idx >> 4;
    int c4 = (idx & 15) * 4;
    int gn = nb + c4;
    if (row < nact1 && gn < NV) {
      f32x4 v = *(const f32x4*)&ts[row][c4];
      *(f32x4*)&out_pred[((size_t)row * NT + t1) * NV + gn] = v;
    }
  }
}

extern "C" void kernel_launch(void* const* d_in, const int* in_sizes, int n_in,
                              void* d_out, int out_size, void* d_ws, size_t ws_size,
                              hipStream_t stream) {
  (void)in_sizes; (void)n_in; (void)out_size; (void)ws_size;
  const float* features  = (const float*)d_in[0];
  const int*   captions  = (const int*)d_in[1];
  const int*   cap_len   = (const int*)d_in[2];
  const float* emb       = (const float*)d_in[3];
  const float* W_enc_att = (const float*)d_in[4];
  const float* b_enc_att = (const float*)d_in[5];
  const float* W_dec_att = (const float*)d_in[6];
  const float* b_dec_att = (const float*)d_in[7];
  const float* w_full    = (const float*)d_in[8];
  const float* b_full    = (const float*)d_in[9];
  const float* W_h0      = (const float*)d_in[10];
  const float* b_h0      = (const float*)d_in[11];
  const float* W_c0      = (const float*)d_in[12];
  const float* b_c0      = (const float*)d_in[13];
  const float* W_beta    = (const float*)d_in[14];
  const float* b_beta    = (const float*)d_in[15];
  const float* W_ih      = (const float*)d_in[16];
  const float* b_ih      = (const float*)d_in[17];
  const float* W_hh      = (const float*)d_in[18];
  const float* b_hh      = (const float*)d_in[19];
  const float* W_fc      = (const float*)d_in[20];
  const float* b_fc      = (const float*)d_in[21];

  float* out      = (float*)d_out;
  float* out_pred = out;
  float* out_cap  = out_pred + (size_t)NB * NT * NV;
  float* out_dlen = out_cap + (size_t)NB * NL;
  float* out_alph = out_dlen + NB;

  char* p = (char*)d_ws;
  auto alloc = [&](size_t nbytes) { void* r = (void*)p; p += (nbytes + 255) & ~(size_t)255; return r; };
  int*   order    = (int*)alloc(NB * 4);
  int*   nact     = (int*)alloc(NT * 4);
  int*   dlen_s   = (int*)alloc(NB * 4);
  u16*   eob      = (u16*)alloc((size_t)NB * NENC * 2);
  float* c        = (float*)alloc((size_t)NB * ND * 4);
  u16*   hb       = (u16*)alloc((size_t)NB * ND * 2);
  u16*   xh0      = (u16*)alloc((size_t)NB * KXH2 * 2);
  u16*   xh1      = (u16*)alloc((size_t)NB * KXH2 * 2);
  u16*   hnewAll  = (u16*)alloc((size_t)NT * NB * ND * 2);
  float* dec_proj = (float*)alloc((size_t)NB * NA * 4);
  float* gate_raw = (float*)alloc((size_t)NB * NENC * 4);
  u16*   featsb   = (u16*)alloc((size_t)NB * NP * NENC * 2);
  u8*    featsb8  = (u8*)alloc((size_t)NB * NP * NENC);
  u16*   encb     = (u16*)alloc((size_t)NB * NP * NA * 2);
  u16*   WencT    = (u16*)alloc((size_t)NA * NENC * 2);
  u16*   WdgT     = (u16*)alloc((size_t)(NA + NENC) * ND * 2);
  u16*   WihTopT  = (u16*)alloc((size_t)NENC * NE * 2);
  u16*   WifgoT2  = (u16*)alloc((size_t)NENC * KXH2 * 2);
  u16*   WfcT     = (u16*)alloc((size_t)NVPAD * ND * 2);
  u16*   WhcT     = (u16*)alloc((size_t)1024 * NENC * 2);
  u16*   embA     = (u16*)alloc((size_t)NT * NB * NE * 2);
  u16*   embAll   = (u16*)alloc((size_t)NT * NB * NENC * 2);

  kSort<<<1, NB, 0, stream>>>(cap_len, captions, order, nact, dlen_s, out_cap, out_dlen);
  kAlphaZero<<<NT, 256, 0, stream>>>(nact, out_alph);
  kPredTail<<<dim3(NB, 16), 256, 0, stream>>>(dlen_s, out_pred);
  kFeats<<<dim3(NP, NB), 256, 0, stream>>>(features, order, featsb, featsb8);
  kTrans<<<dim3(512 / 32, 2048 / 128), 256, 0, stream>>>(W_enc_att, nullptr, WencT, 2048, 512, 0);
  kTrans<<<dim3(2560 / 32, 512 / 128), 256, 0, stream>>>(W_dec_att, W_beta, WdgT, 512, 2560, 1);
  kTrans<<<dim3(2048 / 32, 512 / 128), 256, 0, stream>>>(W_ih, nullptr, WihTopT, 512, 2048, 2);
  kTrans<<<dim3(2048 / 32, 2560 / 128), 256, 0, stream>>>(W_ih, W_hh, WifgoT2, 2560, 2048, 3);
  kTrans<<<dim3(NVPAD / 32, 512 / 128), 256, 0, stream>>>(W_fc, nullptr, WfcT, 512, NVPAD, 4);
  kTrans<<<dim3(1024 / 32, 2048 / 128), 256, 0, stream>>>(W_h0, W_c0, WhcT, 2048, 1024, 5);
  kEmbA<<<dim3(NT, NB), 256, 0, stream>>>(emb, captions, order, embA);
  kEmbGemm<<<dim3(NENC / 64, NT), 256, 0, stream>>>(embA, WihTopT, embAll);
  kEo<<<dim3(NENC / 256, NB), 256, 0, stream>>>(featsb, eob);
  kHC0<<<dim3(1024 / 32, NB / 32), 64, 0, stream>>>(eob, WhcT, b_h0, b_c0, hb, xh0, c);
  kEncProj<<<1568, 256, 0, stream>>>(featsb, WencT, b_enc_att, encb);

  for (int t = 0; t < NT; ++t) {
    u16* xh_r = (t & 1) ? xh1 : xh0;
    u16* xh_w = (t & 1) ? xh0 : xh1;
    kDecGate<<<320, 64, 0, stream>>>(hb, WdgT, b_dec_att, b_beta, nact, t, dec_proj, gate_raw);
    kSAX<<<NB, 512, 0, stream>>>(featsb8, encb, dec_proj, gate_raw, w_full, b_full,
                                 nact, t, xh_r, out_alph);
    kGatesLstm<<<256, 1024, 0, stream>>>(xh_r, WifgoT2, embAll, b_ih, b_hh, nact, t,
                                         c, hb, hnewAll + (size_t)t * NB * ND, xh_w);
  }
  kPredsAll6<<<4160, 256, 0, stream>>>(hnewAll, WfcT, b_fc, nact, out_pred);
}

// Round 18
// 3748.543 us; speedup vs baseline: 1.1786x; 1.1786x over previous
//
#include <hip/hip_runtime.h>
#include <math.h>

#define NB 128
#define NP 196
#define NENC 2048
#define NE 512
#define ND 512
#define NA 512
#define NV 10000
#define NVPAD 10112
#define NL 52
#define NT 51
#define KXH2 2560   // [attw 2048 | h 512]

typedef unsigned short u16;
typedef unsigned char u8;
typedef __attribute__((ext_vector_type(8))) short bf16x8;
typedef __attribute__((ext_vector_type(8))) unsigned short u16x8;
typedef __attribute__((ext_vector_type(4))) float f32x4;

#define MFMA16 __builtin_amdgcn_mfma_f32_16x16x32_bf16

__device__ __forceinline__ float sigmoidf_(float v) { return 1.0f / (1.0f + __expf(-v)); }
__device__ __forceinline__ float b2f(u16 u) { return __uint_as_float(((unsigned int)u) << 16); }
__device__ __forceinline__ u16 f2b(float f) {
  unsigned int u = __float_as_uint(f);
  unsigned int r = (u + 0x7FFFu + ((u >> 16) & 1u)) >> 16;
  return (u16)r;
}

// ---- fp8 e4m3 (OCP) helpers; SEL compile-time constant ----
template <int SEL>
__device__ __forceinline__ float fp8tof(unsigned int data) {
#if __has_builtin(__builtin_amdgcn_cvt_f32_fp8)
  return __builtin_amdgcn_cvt_f32_fp8(data, SEL);
#else
  unsigned int b = (data >> (SEL * 8)) & 0xFFu;
  unsigned int s = (b & 0x80u) << 24;
  unsigned int em = b & 0x7Fu;
  float mag;
  if ((em >> 3) == 0) mag = (float)em * 0.001953125f;
  else mag = __uint_as_float((((em >> 3) + 120) << 23) | ((em & 7u) << 20));
  return __uint_as_float(s | __float_as_uint(mag));
#endif
}
__device__ __forceinline__ u8 ftofp8(float f) {
  unsigned int u = __float_as_uint(f);
  unsigned int s = (u >> 24) & 0x80u;
  float af = fabsf(f);
  if (af >= 448.0f) return (u8)(s | 0x7Eu);
  if (af < 0.015625f) {
    int m = (int)(af * 512.0f + 0.5f);
    if (m >= 8) return (u8)(s | 0x08u);
    return (u8)(s | (unsigned int)m);
  }
  int e = (int)((u >> 23) & 0xFF) - 127;
  unsigned int m3 = (u >> 20) & 7u;
  unsigned int rest = u & 0xFFFFFu;
  if (rest > 0x80000u || (rest == 0x80000u && (m3 & 1u))) { m3++; if (m3 == 8u) { m3 = 0u; e++; } }
  if (e > 8) return (u8)(s | 0x7Eu);
  return (u8)(s | ((unsigned int)(e + 7) << 3) | m3);
}

// ---------------- sort + nact + dlen_sorted ----------------
__global__ void kSort(const int* __restrict__ cap_len, const int* __restrict__ captions,
                      int* __restrict__ order, int* __restrict__ nact,
                      int* __restrict__ dlen_sorted,
                      float* __restrict__ out_cap, float* __restrict__ out_dlen) {
  __shared__ int lens[NB];
  __shared__ int s_dl[NB];
  int tid = threadIdx.x;
  lens[tid] = cap_len[tid];
  __syncthreads();
  int li = lens[tid];
  int r = 0;
  for (int j = 0; j < NB; ++j) {
    int lj = lens[j];
    if (lj > li || (lj == li && j < tid)) r++;
  }
  order[r] = tid;
  s_dl[r] = li - 1;
  dlen_sorted[r] = li - 1;
  out_dlen[r] = (float)(li - 1);
  for (int l = 0; l < NL; ++l)
    out_cap[(size_t)r * NL + l] = (float)captions[(size_t)tid * NL + l];
  __syncthreads();
  if (tid < NT) {
    int cnt = 0;
    for (int j = 0; j < NB; ++j) cnt += (s_dl[j] > tid) ? 1 : 0;
    nact[tid] = cnt;
  }
}

__global__ void kAlphaZero(const int* __restrict__ nact, float* __restrict__ out_alph) {
  int t = blockIdx.x;
  int n0 = nact[t];
  int cnt = (NB - n0) * NP;
  for (int i = threadIdx.x; i < cnt; i += 256) {
    int b = n0 + i / NP;
    int p = i - (i / NP) * NP;
    out_alph[((size_t)b * NT + t) * NP + p] = 0.0f;
  }
}

// ---------------- zero the per-row tail of predictions ----------------
__global__ __launch_bounds__(256) void kPredTail(const int* __restrict__ dlen_sorted,
                                                 float* __restrict__ out_pred) {
  int row = blockIdx.x;
  int d = dlen_sorted[row];
  int cnt = (NT - d) * NV;
  float* base = out_pred + (size_t)row * NT * NV + (size_t)d * NV;
  f32x4 z = {0.0f, 0.0f, 0.0f, 0.0f};
  int start = (blockIdx.y * 256 + threadIdx.x) * 4;
  int step = gridDim.y * 256 * 4;
  for (int i = start; i < cnt; i += step)
    *(f32x4*)&base[i] = z;
}

// ---------------- features gather + bf16 + fp8 ----------------
__global__ void kFeats(const float* __restrict__ features, const int* __restrict__ order,
                       u16* __restrict__ featsb, u8* __restrict__ featsb8) {
  int p = blockIdx.x, b = blockIdx.y, tid = threadIdx.x;
  const float* src = features + ((size_t)order[b] * NP + p) * NENC + tid * 8;
  float4 v0 = *(const float4*)src;
  float4 v1 = *(const float4*)(src + 4);
  u16x8 o;
  o[0] = f2b(v0.x); o[1] = f2b(v0.y); o[2] = f2b(v0.z); o[3] = f2b(v0.w);
  o[4] = f2b(v1.x); o[5] = f2b(v1.y); o[6] = f2b(v1.z); o[7] = f2b(v1.w);
  *(u16x8*)(featsb + ((size_t)b * NP + p) * NENC + tid * 8) = o;
  uint2 q;
  q.x = (unsigned int)ftofp8(v0.x) | ((unsigned int)ftofp8(v0.y) << 8) |
        ((unsigned int)ftofp8(v0.z) << 16) | ((unsigned int)ftofp8(v0.w) << 24);
  q.y = (unsigned int)ftofp8(v1.x) | ((unsigned int)ftofp8(v1.y) << 8) |
        ((unsigned int)ftofp8(v1.z) << 16) | ((unsigned int)ftofp8(v1.w) << 24);
  *(uint2*)(featsb8 + ((size_t)b * NP + p) * NENC + tid * 8) = q;
}

// ---------------- unified LDS-tiled transpose ----------------
__device__ __forceinline__ float tfetch(int mode, int k, int n,
                                        const float* __restrict__ A,
                                        const float* __restrict__ B) {
  switch (mode) {
    case 0: return A[(size_t)k * NA + n];
    case 1: return (n < NA) ? A[(size_t)k * NA + n] : B[(size_t)k * NENC + (n - NA)];
    case 2: return A[(size_t)k * (4 * ND) + (n & 3) * ND + (n >> 2)];
    case 3: {
      int col = (n & 3) * ND + (n >> 2);
      return (k < NENC) ? A[(size_t)(NE + k) * (4 * ND) + col]
                        : B[(size_t)(k - NENC) * (4 * ND) + col];
    }
    case 4: return (n < NV) ? A[(size_t)k * NV + n] : 0.0f;
    default: return (n < NA) ? A[(size_t)k * ND + n] : B[(size_t)k * ND + (n - NA)];
  }
}

__global__ __launch_bounds__(256) void kTrans(const float* __restrict__ A,
                                              const float* __restrict__ B,
                                              u16* __restrict__ dst,
                                              int K, int N, int mode) {
  __shared__ u16 T[32][136];
  int n0 = blockIdx.x * 32, k0 = blockIdx.y * 128;
  int tid = threadIdx.x;
  int c = tid & 31, kr = tid >> 5;
#pragma unroll
  for (int pass = 0; pass < 16; ++pass) {
    int kl = pass * 8 + kr;
    T[c][kl] = f2b(tfetch(mode, k0 + kl, n0 + c, A, B));
  }
  __syncthreads();
  int row = tid >> 3, seg = tid & 7;
  u16x8 v0, v1;
#pragma unroll
  for (int j = 0; j < 8; ++j) { v0[j] = T[row][seg * 16 + j]; v1[j] = T[row][seg * 16 + 8 + j]; }
  *(u16x8*)&dst[(size_t)(n0 + row) * K + k0 + seg * 16] = v0;
  *(u16x8*)&dst[(size_t)(n0 + row) * K + k0 + seg * 16 + 8] = v1;
}

// ---------------- embA gather ----------------
__global__ void kEmbA(const float* __restrict__ emb, const int* __restrict__ captions,
                      const int* __restrict__ order, u16* __restrict__ embA) {
  int t = blockIdx.x, b = blockIdx.y;
  int tok = captions[(size_t)order[b] * NL + t];
  int i = threadIdx.x * 2;
  float2 v = *(const float2*)(emb + (size_t)tok * NE + i);
  unsigned int w0 = (unsigned int)f2b(v.x) | ((unsigned int)f2b(v.y) << 16);
  *(unsigned int*)(embA + ((size_t)t * NB + b) * NE + i) = w0;
}

// ---------------- embAll = embA @ WihTopT ----------------
__global__ __launch_bounds__(256) void kEmbGemm(const u16* __restrict__ A,
                                                const u16* __restrict__ BT,
                                                u16* __restrict__ D) {
  int w = threadIdx.x >> 6, lane = threadIdx.x & 63;
  int lr = lane & 15, lg = lane >> 4;
  int mb = blockIdx.y * 128 + w * 32;
  int nb = blockIdx.x * 64;
  f32x4 acc[2][4] = {};
  const u16* a0 = A + (size_t)(mb + lr) * NE + lg * 8;
  const u16* a1 = a0 + 16 * NE;
  const u16* b0 = BT + (size_t)(nb + lr) * NE + lg * 8;
  for (int k0 = 0; k0 < NE; k0 += 32) {
    bf16x8 af0 = *(const bf16x8*)(a0 + k0);
    bf16x8 af1 = *(const bf16x8*)(a1 + k0);
#pragma unroll
    for (int nt = 0; nt < 4; ++nt) {
      bf16x8 bf = *(const bf16x8*)(b0 + (size_t)nt * 16 * NE + k0);
      acc[0][nt] = MFMA16(af0, bf, acc[0][nt], 0, 0, 0);
      acc[1][nt] = MFMA16(af1, bf, acc[1][nt], 0, 0, 0);
    }
  }
#pragma unroll
  for (int mt = 0; mt < 2; ++mt)
#pragma unroll
    for (int nt = 0; nt < 4; ++nt)
#pragma unroll
      for (int j = 0; j < 4; ++j) {
        int row = mb + mt * 16 + lg * 4 + j;
        int col = nb + nt * 16 + lr;
        D[(size_t)row * NENC + col] = f2b(acc[mt][nt][j]);
      }
}

// ---------------- eo = mean over P ----------------
__global__ void kEo(const u16* __restrict__ featsb, u16* __restrict__ eob) {
  int e = blockIdx.x * 256 + threadIdx.x;
  int b = blockIdx.y;
  const u16* f = featsb + (size_t)b * NP * NENC + e;
  float s = 0.0f;
  for (int p = 0; p < NP; ++p) s += b2f(f[(size_t)p * NENC]);
  eob[(size_t)b * NENC + e] = f2b(s * (1.0f / NP));
}

// ---------------- h0/c0 via MFMA ----------------
__global__ __launch_bounds__(64) void kHC0(const u16* __restrict__ eob,
                                           const u16* __restrict__ BT,
                                           const float* __restrict__ b_h0,
                                           const float* __restrict__ b_c0,
                                           u16* __restrict__ hb, u16* __restrict__ xh0,
                                           float* __restrict__ c) {
  int lane = threadIdx.x;
  int lr = lane & 15, lg = lane >> 4;
  int mb = blockIdx.y * 32, nb = blockIdx.x * 32;
  f32x4 acc[2][2] = {};
  const u16* a0 = eob + (size_t)(mb + lr) * NENC + lg * 8;
  const u16* a1 = a0 + 16 * NENC;
  const u16* b0 = BT + (size_t)(nb + lr) * NENC + lg * 8;
  const u16* b1 = b0 + 16 * NENC;
#pragma unroll 4
  for (int k0 = 0; k0 < NENC; k0 += 32) {
    bf16x8 af0 = *(const bf16x8*)(a0 + k0);
    bf16x8 af1 = *(const bf16x8*)(a1 + k0);
    bf16x8 bv0 = *(const bf16x8*)(b0 + k0);
    bf16x8 bv1 = *(const bf16x8*)(b1 + k0);
    acc[0][0] = MFMA16(af0, bv0, acc[0][0], 0, 0, 0);
    acc[1][0] = MFMA16(af1, bv0, acc[1][0], 0, 0, 0);
    acc[0][1] = MFMA16(af0, bv1, acc[0][1], 0, 0, 0);
    acc[1][1] = MFMA16(af1, bv1, acc[1][1], 0, 0, 0);
  }
#pragma unroll
  for (int mt = 0; mt < 2; ++mt)
#pragma unroll
    for (int nt = 0; nt < 2; ++nt)
#pragma unroll
      for (int j = 0; j < 4; ++j) {
        int row = mb + mt * 16 + lg * 4 + j;
        int n = nb + nt * 16 + lr;
        if (n < NA) {
          u16 hv = f2b(acc[mt][nt][j] + b_h0[n]);
          hb[(size_t)row * ND + n] = hv;
          xh0[(size_t)row * KXH2 + NENC + n] = hv;
        } else {
          c[(size_t)row * ND + (n - NA)] = acc[mt][nt][j] + b_c0[n - NA];
        }
      }
}

// ---------------- enc_proj: 128x64 tiles, dbuf LDS A, XCD swizzle ----------------
__global__ __launch_bounds__(256) void kEncProj(const u16* __restrict__ A,
                                                const u16* __restrict__ BT,
                                                const float* __restrict__ bias,
                                                u16* __restrict__ D) {
  __shared__ u16 As[2][128][72];
  int lin = ((int)blockIdx.x % 8) * 196 + (int)blockIdx.x / 8;  // 1568 = 8*196
  int mt = lin >> 3, ntile = lin & 7;
  int mb = mt * 128, nb = ntile * 64;
  int tid = threadIdx.x;
  int w = tid >> 6, lane = tid & 63;
  int lr = lane & 15, lg = lane >> 4;

  int arow[4], akp[4];
  const u16* aptr[4];
#pragma unroll
  for (int i = 0; i < 4; ++i) {
    int idx = i * 256 + tid;
    arow[i] = idx >> 3;
    akp[i] = idx & 7;
    aptr[i] = A + (size_t)(mb + arow[i]) * NENC + akp[i] * 8;
  }
  u16x8 s0 = *(const u16x8*)(aptr[0]);
  u16x8 s1 = *(const u16x8*)(aptr[1]);
  u16x8 s2 = *(const u16x8*)(aptr[2]);
  u16x8 s3 = *(const u16x8*)(aptr[3]);
  *(u16x8*)&As[0][arow[0]][akp[0] * 8] = s0;
  *(u16x8*)&As[0][arow[1]][akp[1] * 8] = s1;
  *(u16x8*)&As[0][arow[2]][akp[2] * 8] = s2;
  *(u16x8*)&As[0][arow[3]][akp[3] * 8] = s3;

  f32x4 acc[2][4] = {};
  const u16* bbase = BT + (size_t)(nb + lr) * NENC + lg * 8;
  int cur = 0;
  int r0 = w * 32 + lr;

  for (int k0 = 0; k0 < NENC; k0 += 64) {
    __syncthreads();
    bool more = (k0 + 64 < NENC);
    if (more) {
      s0 = *(const u16x8*)(aptr[0] + k0 + 64);
      s1 = *(const u16x8*)(aptr[1] + k0 + 64);
      s2 = *(const u16x8*)(aptr[2] + k0 + 64);
      s3 = *(const u16x8*)(aptr[3] + k0 + 64);
    }
#pragma unroll
    for (int kh = 0; kh < 2; ++kh) {
      bf16x8 af0 = *(const bf16x8*)&As[cur][r0][kh * 32 + lg * 8];
      bf16x8 af1 = *(const bf16x8*)&As[cur][r0 + 16][kh * 32 + lg * 8];
#pragma unroll
      for (int nt = 0; nt < 4; ++nt) {
        bf16x8 bf = *(const bf16x8*)(bbase + (size_t)nt * 16 * NENC + k0 + kh * 32);
        acc[0][nt] = MFMA16(af0, bf, acc[0][nt], 0, 0, 0);
        acc[1][nt] = MFMA16(af1, bf, acc[1][nt], 0, 0, 0);
      }
    }
    if (more) {
      *(u16x8*)&As[cur ^ 1][arow[0]][akp[0] * 8] = s0;
      *(u16x8*)&As[cur ^ 1][arow[1]][akp[1] * 8] = s1;
      *(u16x8*)&As[cur ^ 1][arow[2]][akp[2] * 8] = s2;
      *(u16x8*)&As[cur ^ 1][arow[3]][akp[3] * 8] = s3;
    }
    cur ^= 1;
  }
  __syncthreads();
  u16* eps = (u16*)As;             // [128][72]
#pragma unroll
  for (int m2 = 0; m2 < 2; ++m2)
#pragma unroll
    for (int nt = 0; nt < 4; ++nt)
#pragma unroll
      for (int j = 0; j < 4; ++j) {
        int rloc = w * 32 + m2 * 16 + lg * 4 + j;
        int col = nt * 16 + lr;
        eps[rloc * 72 + col] = f2b(acc[m2][nt][j] + bias[nb + col]);
      }
  __syncthreads();
#pragma unroll
  for (int i = 0; i < 4; ++i) {
    int idx = i * 256 + tid;
    int row = idx >> 3, seg = idx & 7;
    *(u16x8*)&D[(size_t)(mb + row) * NA + nb + seg * 8] = *(u16x8*)&eps[row * 72 + seg * 8];
  }
}

// ---------------- kDecGate (R15 grid) ----------------
__global__ __launch_bounds__(64) void kDecGate(const u16* __restrict__ hb,
                                               const u16* __restrict__ BT,
                                               const float* __restrict__ b_dec,
                                               const float* __restrict__ b_beta,
                                               const int* __restrict__ nact, int t,
                                               float* __restrict__ dec_proj,
                                               float* __restrict__ gate_raw) {
  int nact_t = nact[t];
  int mb = blockIdx.y * 32;
  if (mb >= nact_t) return;
  int lane = threadIdx.x;
  int lr = lane & 15, lg = lane >> 4;
  int nb = blockIdx.x * 32;
  f32x4 acc[2][2] = {};
  const u16* a0 = hb + (size_t)(mb + lr) * ND + lg * 8;
  const u16* a1 = a0 + 16 * ND;
  const u16* b0 = BT + (size_t)(nb + lr) * ND + lg * 8;
  const u16* b1 = b0 + 16 * ND;
#pragma unroll 4
  for (int k0 = 0; k0 < ND; k0 += 32) {
    bf16x8 af0 = *(const bf16x8*)(a0 + k0);
    bf16x8 af1 = *(const bf16x8*)(a1 + k0);
    bf16x8 bv0 = *(const bf16x8*)(b0 + k0);
    bf16x8 bv1 = *(const bf16x8*)(b1 + k0);
    acc[0][0] = MFMA16(af0, bv0, acc[0][0], 0, 0, 0);
    acc[1][0] = MFMA16(af1, bv0, acc[1][0], 0, 0, 0);
    acc[0][1] = MFMA16(af0, bv1, acc[0][1], 0, 0, 0);
    acc[1][1] = MFMA16(af1, bv1, acc[1][1], 0, 0, 0);
  }
#pragma unroll
  for (int mt = 0; mt < 2; ++mt)
#pragma unroll
    for (int nt = 0; nt < 2; ++nt)
#pragma unroll
      for (int j = 0; j < 4; ++j) {
        int row = mb + mt * 16 + lg * 4 + j;
        int n = nb + nt * 16 + lr;
        if (n < NA)
          dec_proj[(size_t)row * NA + n] = acc[mt][nt][j] + b_dec[n];
        else
          gate_raw[(size_t)row * NENC + (n - NA)] = acc[mt][nt][j] + b_beta[n - NA];
      }
}

// ---------------- kSAX: R15 structure, fp8 attw reads (2 cols/thread) ----------------
__global__ __launch_bounds__(512) void kSAX(const u8* __restrict__ featsb8,
                                            const u16* __restrict__ encb,
                                            const float* __restrict__ dec_proj,
                                            const float* __restrict__ gate_raw,
                                            const float* __restrict__ w_full,
                                            const float* __restrict__ b_full,
                                            const int* __restrict__ nact, int t,
                                            u16* __restrict__ xh_w,
                                            float* __restrict__ out_alph) {
  int b = blockIdx.x, r = blockIdx.y, tid = threadIdx.x;
  if (b >= nact[t]) return;
  __shared__ float s_dp[NA], s_wf[NA], s_al[NP + 12], red[16];
  if (tid < NA) { s_dp[tid] = dec_proj[(size_t)b * NA + tid]; s_wf[tid] = w_full[tid]; }
  __syncthreads();
  int wave = tid >> 6, lane = tid & 63;
  float bf_ = b_full[0];
  for (int p = wave; p < NP; p += 8) {
    const u16* ep = encb + ((size_t)b * NP + p) * NA + lane * 8;
    u16x8 v = *(const u16x8*)ep;
    float acc = 0.0f;
#pragma unroll
    for (int j = 0; j < 8; ++j) {
      int a = lane * 8 + j;
      float vv = b2f(v[j]) + s_dp[a];
      acc += fmaxf(vv, 0.0f) * s_wf[a];
    }
#pragma unroll
    for (int off = 32; off; off >>= 1) acc += __shfl_down(acc, off);
    if (lane == 0) s_al[p] = acc + bf_;
  }
  __syncthreads();
  float mx = (tid < NP) ? s_al[tid] : -3.4e38f;
#pragma unroll
  for (int off = 32; off; off >>= 1) mx = fmaxf(mx, __shfl_down(mx, off));
  if (lane == 0) red[wave] = mx;
  __syncthreads();
  if (tid == 0) {
    float m = red[0];
    for (int i = 1; i < 8; ++i) m = fmaxf(m, red[i]);
    red[0] = m;
  }
  __syncthreads();
  float m2v = red[0];
  float e = 0.0f;
  if (tid < NP) { e = __expf(s_al[tid] - m2v); s_al[tid] = e; }
#pragma unroll
  for (int off = 32; off; off >>= 1) e += __shfl_down(e, off);
  if (lane == 0) red[8 + wave] = e;
  __syncthreads();
  if (tid == 0) {
    float s = 0.0f;
    for (int i = 0; i < 8; ++i) s += red[8 + i];
    red[8] = 1.0f / s;
  }
  __syncthreads();
  float inv = red[8];
  if (tid < NP) {
    float al = s_al[tid] * inv;
    s_al[tid] = al;
    if (r == 0) out_alph[((size_t)b * NT + t) * NP + tid] = al;
  }
  __syncthreads();
  // attw slice [r*1024, r*1024+1024): 2 fp8 cols per thread
  int e0 = r * 1024 + tid * 2;
  float ac0 = 0.0f, ac1 = 0.0f;
  const u8* fb = featsb8 + (size_t)b * NP * NENC + e0;
#pragma unroll 4
  for (int p = 0; p < NP; ++p) {
    unsigned int v = (unsigned int)(*(const u16*)(fb + (size_t)p * NENC));
    float al = s_al[p];
    ac0 += al * fp8tof<0>(v);
    ac1 += al * fp8tof<1>(v);
  }
  float g0 = sigmoidf_(gate_raw[(size_t)b * NENC + e0]);
  float g1 = sigmoidf_(gate_raw[(size_t)b * NENC + e0 + 1]);
  unsigned int wo = (unsigned int)f2b(ac0 * g0) | ((unsigned int)f2b(ac1 * g1) << 16);
  *(unsigned int*)(xh_w + (size_t)b * KXH2 + e0) = wo;
}

// ---------------- kGatesLstm: R15 grid (blockIdx direct) ----------------
__global__ __launch_bounds__(1024) void kGatesLstm(const u16* __restrict__ xh_r,
                                                   const u16* __restrict__ WifgoT2,
                                                   const u16* __restrict__ embAll,
                                                   const float* __restrict__ b_ih,
                                                   const float* __restrict__ b_hh,
                                                   const int* __restrict__ nact, int t,
                                                   float* __restrict__ cst,
                                                   u16* __restrict__ hb,
                                                   u16* __restrict__ hnewAll_t,
                                                   u16* __restrict__ xh_w) {
  __shared__ float smem[8 * 32 * 33];
  int nact_t = nact[t];
  int tid = threadIdx.x;
  int w = tid >> 6, lane = tid & 63;
  int lr = lane & 15, lg = lane >> 4;
  int rt = blockIdx.x & 3, ct = blockIdx.x >> 2;
  int mb = rt * 32, nb = ct * 32;
  int kq = w >> 1, mh = w & 1;
  if (mb < nact_t) {
    f32x4 acc0 = {}, acc1 = {};
    const u16* pa = xh_r + (size_t)(mb + mh * 16 + lr) * KXH2 + kq * 320 + lg * 8;
    const u16* pb0 = WifgoT2 + (size_t)(nb + lr) * KXH2 + kq * 320 + lg * 8;
    const u16* pb1 = pb0 + (size_t)16 * KXH2;
#pragma unroll
    for (int k0 = 0; k0 < 320; k0 += 32) {
      bf16x8 af = *(const bf16x8*)(pa + k0);
      bf16x8 bv0 = *(const bf16x8*)(pb0 + k0);
      bf16x8 bv1 = *(const bf16x8*)(pb1 + k0);
      acc0 = MFMA16(af, bv0, acc0, 0, 0, 0);
      acc1 = MFMA16(af, bv1, acc1, 0, 0, 0);
    }
#pragma unroll
    for (int j = 0; j < 4; ++j) {
      int rr = kq * 32 + mh * 16 + lg * 4 + j;
      smem[rr * 33 + lr] = acc0[j];
      smem[rr * 33 + 16 + lr] = acc1[j];
    }
  }
  __syncthreads();
  if (tid < 256) {
    int row = tid >> 3, dl = tid & 7;
    int grow = mb + row;
    int d = ct * 8 + dl;
    size_t off = (size_t)grow * ND + d;
    if (grow < nact_t) {
      float g4[4];
#pragma unroll
      for (int g = 0; g < 4; ++g) {
        int col = dl * 4 + g;
        float s = 0.0f;
#pragma unroll
        for (int q = 0; q < 8; ++q) s += smem[(q * 32 + row) * 33 + col];
        s += b2f(embAll[((size_t)t * NB + grow) * NENC + nb + col]);
        g4[g] = s;
      }
      float gi = g4[0] + b_ih[d] + b_hh[d];
      float gf = g4[1] + b_ih[ND + d] + b_hh[ND + d];
      float gg = g4[2] + b_ih[2 * ND + d] + b_hh[2 * ND + d];
      float go = g4[3] + b_ih[3 * ND + d] + b_hh[3 * ND + d];
      float cn = sigmoidf_(gf) * cst[off] + sigmoidf_(gi) * tanhf(gg);
      float hn = sigmoidf_(go) * tanhf(cn);
      u16 hv = f2b(hn);
      cst[off] = cn;
      hb[off] = hv;
      hnewAll_t[off] = hv;
      xh_w[(size_t)grow * KXH2 + NENC + d] = hv;
    } else {
      xh_w[(size_t)grow * KXH2 + NENC + d] = hb[off];
    }
  }
}

// ---------------- preds GEMM: t-paired blocks (B reuse x2), XCD-chunked ----------------
__global__ __launch_bounds__(256) void kPredsAll6(const u16* __restrict__ hnewAll,
                                                  const u16* __restrict__ BT,
                                                  const float* __restrict__ b_fc,
                                                  const int* __restrict__ nact,
                                                  float* __restrict__ out_pred) {
  __shared__ float ts[128][68];
  int lin = ((int)blockIdx.x & 7) * 520 + ((int)blockIdx.x >> 3);
  if (lin >= 158 * 26) return;
  int nbi = lin / 26;
  int tp = lin - nbi * 26;
  int t0 = tp * 2;
  int t1 = t0 + 1;
  bool has1 = (t1 < NT);
  int nb = nbi * 64;
  int nact0 = nact[t0];
  int nact1 = has1 ? nact[t1] : 0;
  int w = threadIdx.x >> 6, lane = threadIdx.x & 63;
  int lr = lane & 15, lg = lane >> 4;
  int mb = w * 32;
  f32x4 acc0[2][4] = {};
  f32x4 acc1[2][4] = {};
  bool do1 = has1 && (mb < nact1);
  if (mb < nact0) {
    const u16* a0 = hnewAll + (size_t)t0 * NB * ND + (size_t)(mb + lr) * ND + lg * 8;
    const u16* a1 = a0 + 16 * ND;
    const u16* a0b = a0 + (size_t)NB * ND;
    const u16* a1b = a1 + (size_t)NB * ND;
    const u16* b0 = BT + (size_t)(nb + lr) * ND + lg * 8;
    for (int k0 = 0; k0 < ND; k0 += 32) {
      bf16x8 bf0 = *(const bf16x8*)(b0 + k0);
      bf16x8 bf1 = *(const bf16x8*)(b0 + (size_t)16 * ND + k0);
      bf16x8 bf2 = *(const bf16x8*)(b0 + (size_t)32 * ND + k0);
      bf16x8 bf3 = *(const bf16x8*)(b0 + (size_t)48 * ND + k0);
      bf16x8 af0 = *(const bf16x8*)(a0 + k0);
      bf16x8 af1 = *(const bf16x8*)(a1 + k0);
      acc0[0][0] = MFMA16(af0, bf0, acc0[0][0], 0, 0, 0);
      acc0[1][0] = MFMA16(af1, bf0, acc0[1][0], 0, 0, 0);
      acc0[0][1] = MFMA16(af0, bf1, acc0[0][1], 0, 0, 0);
      acc0[1][1] = MFMA16(af1, bf1, acc0[1][1], 0, 0, 0);
      acc0[0][2] = MFMA16(af0, bf2, acc0[0][2], 0, 0, 0);
      acc0[1][2] = MFMA16(af1, bf2, acc0[1][2], 0, 0, 0);
      acc0[0][3] = MFMA16(af0, bf3, acc0[0][3], 0, 0, 0);
      acc0[1][3] = MFMA16(af1, bf3, acc0[1][3], 0, 0, 0);
      if (do1) {
        bf16x8 ag0 = *(const bf16x8*)(a0b + k0);
        bf16x8 ag1 = *(const bf16x8*)(a1b + k0);
        acc1[0][0] = MFMA16(ag0, bf0, acc1[0][0], 0, 0, 0);
        acc1[1][0] = MFMA16(ag1, bf0, acc1[1][0], 0, 0, 0);
        acc1[0][1] = MFMA16(ag0, bf1, acc1[0][1], 0, 0, 0);
        acc1[1][1] = MFMA16(ag1, bf1, acc1[1][1], 0, 0, 0);
        acc1[0][2] = MFMA16(ag0, bf2, acc1[0][2], 0, 0, 0);
        acc1[1][2] = MFMA16(ag1, bf2, acc1[1][2], 0, 0, 0);
        acc1[0][3] = MFMA16(ag0, bf3, acc1[0][3], 0, 0, 0);
        acc1[1][3] = MFMA16(ag1, bf3, acc1[1][3], 0, 0, 0);
      }
    }
  }
  int tid = threadIdx.x;
#pragma unroll
  for (int mt = 0; mt < 2; ++mt)
#pragma unroll
    for (int nt = 0; nt < 4; ++nt)
#pragma unroll
      for (int j = 0; j < 4; ++j) {
        int row = mb + mt * 16 + lg * 4 + j;
        int gn = nb + nt * 16 + lr;
        float bias = (gn < NV) ? b_fc[gn] : 0.0f;
        ts[row][nt * 16 + lr] = acc0[mt][nt][j] + bias;
      }
  __syncthreads();
#pragma unroll
  for (int i = 0; i < 8; ++i) {
    int idx = i * 256 + tid;
    int row = idx >> 4;
    int c4 = (idx & 15) * 4;
    int gn = nb + c4;
    if (row < nact0 && gn < NV) {
      f32x4 v = *(const f32x4*)&ts[row][c4];
      *(f32x4*)&out_pred[((size_t)row * NT + t0) * NV + gn] = v;
    }
  }
  if (!has1) return;
  __syncthreads();
#pragma unroll
  for (int mt = 0; mt < 2; ++mt)
#pragma unroll
    for (int nt = 0; nt < 4; ++nt)
#pragma unroll
      for (int j = 0; j < 4; ++j) {
        int row = mb + mt * 16 + lg * 4 + j;
        int gn = nb + nt * 16 + lr;
        float bias = (gn < NV) ? b_fc[gn] : 0.0f;
        ts[row][nt * 16 + lr] = acc1[mt][nt][j] + bias;
      }
  __syncthreads();
#pragma unroll
  for (int i = 0; i < 8; ++i) {
    int idx = i * 256 + tid;
    int row = idx >> 4;
    int c4 = (idx & 15) * 4;
    int gn = nb + c4;
    if (row < nact1 && gn < NV) {
      f32x4 v = *(const f32x4*)&ts[row][c4];
      *(f32x4*)&out_pred[((size_t)row * NT + t1) * NV + gn] = v;
    }
  }
}

extern "C" void kernel_launch(void* const* d_in, const int* in_sizes, int n_in,
                              void* d_out, int out_size, void* d_ws, size_t ws_size,
                              hipStream_t stream) {
  (void)in_sizes; (void)n_in; (void)out_size; (void)ws_size;
  const float* features  = (const float*)d_in[0];
  const int*   captions  = (const int*)d_in[1];
  const int*   cap_len   = (const int*)d_in[2];
  const float* emb       = (const float*)d_in[3];
  const float* W_enc_att = (const float*)d_in[4];
  const float* b_enc_att = (const float*)d_in[5];
  const float* W_dec_att = (const float*)d_in[6];
  const float* b_dec_att = (const float*)d_in[7];
  const float* w_full    = (const float*)d_in[8];
  const float* b_full    = (const float*)d_in[9];
  const float* W_h0      = (const float*)d_in[10];
  const float* b_h0      = (const float*)d_in[11];
  const float* W_c0      = (const float*)d_in[12];
  const float* b_c0      = (const float*)d_in[13];
  const float* W_beta    = (const float*)d_in[14];
  const float* b_beta    = (const float*)d_in[15];
  const float* W_ih      = (const float*)d_in[16];
  const float* b_ih      = (const float*)d_in[17];
  const float* W_hh      = (const float*)d_in[18];
  const float* b_hh      = (const float*)d_in[19];
  const float* W_fc      = (const float*)d_in[20];
  const float* b_fc      = (const float*)d_in[21];

  float* out      = (float*)d_out;
  float* out_pred = out;
  float* out_cap  = out_pred + (size_t)NB * NT * NV;
  float* out_dlen = out_cap + (size_t)NB * NL;
  float* out_alph = out_dlen + NB;

  char* p = (char*)d_ws;
  auto alloc = [&](size_t nbytes) { void* r = (void*)p; p += (nbytes + 255) & ~(size_t)255; return r; };
  int*   order    = (int*)alloc(NB * 4);
  int*   nact     = (int*)alloc(NT * 4);
  int*   dlen_s   = (int*)alloc(NB * 4);
  u16*   eob      = (u16*)alloc((size_t)NB * NENC * 2);
  float* c        = (float*)alloc((size_t)NB * ND * 4);
  u16*   hb       = (u16*)alloc((size_t)NB * ND * 2);
  u16*   xh0      = (u16*)alloc((size_t)NB * KXH2 * 2);
  u16*   xh1      = (u16*)alloc((size_t)NB * KXH2 * 2);
  u16*   hnewAll  = (u16*)alloc((size_t)NT * NB * ND * 2);
  float* dec_proj = (float*)alloc((size_t)NB * NA * 4);
  float* gate_raw = (float*)alloc((size_t)NB * NENC * 4);
  u16*   featsb   = (u16*)alloc((size_t)NB * NP * NENC * 2);
  u8*    featsb8  = (u8*)alloc((size_t)NB * NP * NENC);
  u16*   encb     = (u16*)alloc((size_t)NB * NP * NA * 2);
  u16*   WencT    = (u16*)alloc((size_t)NA * NENC * 2);
  u16*   WdgT     = (u16*)alloc((size_t)(NA + NENC) * ND * 2);
  u16*   WihTopT  = (u16*)alloc((size_t)NENC * NE * 2);
  u16*   WifgoT2  = (u16*)alloc((size_t)NENC * KXH2 * 2);
  u16*   WfcT     = (u16*)alloc((size_t)NVPAD * ND * 2);
  u16*   WhcT     = (u16*)alloc((size_t)1024 * NENC * 2);
  u16*   embA     = (u16*)alloc((size_t)NT * NB * NE * 2);
  u16*   embAll   = (u16*)alloc((size_t)NT * NB * NENC * 2);

  kSort<<<1, NB, 0, stream>>>(cap_len, captions, order, nact, dlen_s, out_cap, out_dlen);
  kAlphaZero<<<NT, 256, 0, stream>>>(nact, out_alph);
  kPredTail<<<dim3(NB, 16), 256, 0, stream>>>(dlen_s, out_pred);
  kFeats<<<dim3(NP, NB), 256, 0, stream>>>(features, order, featsb, featsb8);
  kTrans<<<dim3(512 / 32, 2048 / 128), 256, 0, stream>>>(W_enc_att, nullptr, WencT, 2048, 512, 0);
  kTrans<<<dim3(2560 / 32, 512 / 128), 256, 0, stream>>>(W_dec_att, W_beta, WdgT, 512, 2560, 1);
  kTrans<<<dim3(2048 / 32, 512 / 128), 256, 0, stream>>>(W_ih, nullptr, WihTopT, 512, 2048, 2);
  kTrans<<<dim3(2048 / 32, 2560 / 128), 256, 0, stream>>>(W_ih, W_hh, WifgoT2, 2560, 2048, 3);
  kTrans<<<dim3(NVPAD / 32, 512 / 128), 256, 0, stream>>>(W_fc, nullptr, WfcT, 512, NVPAD, 4);
  kTrans<<<dim3(1024 / 32, 2048 / 128), 256, 0, stream>>>(W_h0, W_c0, WhcT, 2048, 1024, 5);
  kEmbA<<<dim3(NT, NB), 256, 0, stream>>>(emb, captions, order, embA);
  kEmbGemm<<<dim3(NENC / 64, NT), 256, 0, stream>>>(embA, WihTopT, embAll);
  kEo<<<dim3(NENC / 256, NB), 256, 0, stream>>>(featsb, eob);
  kHC0<<<dim3(1024 / 32, NB / 32), 64, 0, stream>>>(eob, WhcT, b_h0, b_c0, hb, xh0, c);
  kEncProj<<<1568, 256, 0, stream>>>(featsb, WencT, b_enc_att, encb);

  for (int t = 0; t < NT; ++t) {
    u16* xh_r = (t & 1) ? xh1 : xh0;
    u16* xh_w = (t & 1) ? xh0 : xh1;
    kDecGate<<<dim3((NA + NENC) / 32, 4), 64, 0, stream>>>(hb, WdgT, b_dec_att, b_beta,
                                                           nact, t, dec_proj, gate_raw);
    kSAX<<<dim3(NB, 2), 512, 0, stream>>>(featsb8, encb, dec_proj, gate_raw, w_full, b_full,
                                          nact, t, xh_r, out_alph);
    kGatesLstm<<<256, 1024, 0, stream>>>(xh_r, WifgoT2, embAll, b_ih, b_hh, nact, t,
                                         c, hb, hnewAll + (size_t)t * NB * ND, xh_w);
  }
  kPredsAll6<<<4160, 256, 0, stream>>>(hnewAll, WfcT, b_fc, nact, out_pred);
}

// Round 19
// 3748.468 us; speedup vs baseline: 1.1787x; 1.0000x over previous
//
#include <hip/hip_runtime.h>
#include <math.h>

#define NB 128
#define NP 196
#define NENC 2048
#define NE 512
#define ND 512
#define NA 512
#define NV 10000
#define NVPAD 10112
#define NL 52
#define NT 51
#define KXH2 2560   // [attw 2048 | h 512]

typedef unsigned short u16;
typedef unsigned char u8;
typedef __attribute__((ext_vector_type(8))) short bf16x8;
typedef __attribute__((ext_vector_type(8))) unsigned short u16x8;
typedef __attribute__((ext_vector_type(4))) float f32x4;

#define MFMA16 __builtin_amdgcn_mfma_f32_16x16x32_bf16

__device__ __forceinline__ float sigmoidf_(float v) { return 1.0f / (1.0f + __expf(-v)); }
__device__ __forceinline__ float b2f(u16 u) { return __uint_as_float(((unsigned int)u) << 16); }
__device__ __forceinline__ u16 f2b(float f) {
  unsigned int u = __float_as_uint(f);
  unsigned int r = (u + 0x7FFFu + ((u >> 16) & 1u)) >> 16;
  return (u16)r;
}

// ---- fp8 e4m3 (OCP) helpers; SEL compile-time constant ----
template <int SEL>
__device__ __forceinline__ float fp8tof(unsigned int data) {
#if __has_builtin(__builtin_amdgcn_cvt_f32_fp8)
  return __builtin_amdgcn_cvt_f32_fp8(data, SEL);
#else
  unsigned int b = (data >> (SEL * 8)) & 0xFFu;
  unsigned int s = (b & 0x80u) << 24;
  unsigned int em = b & 0x7Fu;
  float mag;
  if ((em >> 3) == 0) mag = (float)em * 0.001953125f;
  else mag = __uint_as_float((((em >> 3) + 120) << 23) | ((em & 7u) << 20));
  return __uint_as_float(s | __float_as_uint(mag));
#endif
}
__device__ __forceinline__ u8 ftofp8(float f) {
  unsigned int u = __float_as_uint(f);
  unsigned int s = (u >> 24) & 0x80u;
  float af = fabsf(f);
  if (af >= 448.0f) return (u8)(s | 0x7Eu);
  if (af < 0.015625f) {
    int m = (int)(af * 512.0f + 0.5f);
    if (m >= 8) return (u8)(s | 0x08u);
    return (u8)(s | (unsigned int)m);
  }
  int e = (int)((u >> 23) & 0xFF) - 127;
  unsigned int m3 = (u >> 20) & 7u;
  unsigned int rest = u & 0xFFFFFu;
  if (rest > 0x80000u || (rest == 0x80000u && (m3 & 1u))) { m3++; if (m3 == 8u) { m3 = 0u; e++; } }
  if (e > 8) return (u8)(s | 0x7Eu);
  return (u8)(s | ((unsigned int)(e + 7) << 3) | m3);
}

// ---------------- sort + nact + dlen_sorted ----------------
__global__ void kSort(const int* __restrict__ cap_len, const int* __restrict__ captions,
                      int* __restrict__ order, int* __restrict__ nact,
                      int* __restrict__ dlen_sorted,
                      float* __restrict__ out_cap, float* __restrict__ out_dlen) {
  __shared__ int lens[NB];
  __shared__ int s_dl[NB];
  int tid = threadIdx.x;
  lens[tid] = cap_len[tid];
  __syncthreads();
  int li = lens[tid];
  int r = 0;
  for (int j = 0; j < NB; ++j) {
    int lj = lens[j];
    if (lj > li || (lj == li && j < tid)) r++;
  }
  order[r] = tid;
  s_dl[r] = li - 1;
  dlen_sorted[r] = li - 1;
  out_dlen[r] = (float)(li - 1);
  for (int l = 0; l < NL; ++l)
    out_cap[(size_t)r * NL + l] = (float)captions[(size_t)tid * NL + l];
  __syncthreads();
  if (tid < NT) {
    int cnt = 0;
    for (int j = 0; j < NB; ++j) cnt += (s_dl[j] > tid) ? 1 : 0;
    nact[tid] = cnt;
  }
}

__global__ void kAlphaZero(const int* __restrict__ nact, float* __restrict__ out_alph) {
  int t = blockIdx.x;
  int n0 = nact[t];
  int cnt = (NB - n0) * NP;
  for (int i = threadIdx.x; i < cnt; i += 256) {
    int b = n0 + i / NP;
    int p = i - (i / NP) * NP;
    out_alph[((size_t)b * NT + t) * NP + p] = 0.0f;
  }
}

// ---------------- zero the per-row tail of predictions ----------------
__global__ __launch_bounds__(256) void kPredTail(const int* __restrict__ dlen_sorted,
                                                 float* __restrict__ out_pred) {
  int row = blockIdx.x;
  int d = dlen_sorted[row];
  int cnt = (NT - d) * NV;
  float* base = out_pred + (size_t)row * NT * NV + (size_t)d * NV;
  f32x4 z = {0.0f, 0.0f, 0.0f, 0.0f};
  int start = (blockIdx.y * 256 + threadIdx.x) * 4;
  int step = gridDim.y * 256 * 4;
  for (int i = start; i < cnt; i += step)
    *(f32x4*)&base[i] = z;
}

// ---------------- features gather + bf16 + fp8 ----------------
__global__ void kFeats(const float* __restrict__ features, const int* __restrict__ order,
                       u16* __restrict__ featsb, u8* __restrict__ featsb8) {
  int p = blockIdx.x, b = blockIdx.y, tid = threadIdx.x;
  const float* src = features + ((size_t)order[b] * NP + p) * NENC + tid * 8;
  float4 v0 = *(const float4*)src;
  float4 v1 = *(const float4*)(src + 4);
  u16x8 o;
  o[0] = f2b(v0.x); o[1] = f2b(v0.y); o[2] = f2b(v0.z); o[3] = f2b(v0.w);
  o[4] = f2b(v1.x); o[5] = f2b(v1.y); o[6] = f2b(v1.z); o[7] = f2b(v1.w);
  *(u16x8*)(featsb + ((size_t)b * NP + p) * NENC + tid * 8) = o;
  uint2 q;
  q.x = (unsigned int)ftofp8(v0.x) | ((unsigned int)ftofp8(v0.y) << 8) |
        ((unsigned int)ftofp8(v0.z) << 16) | ((unsigned int)ftofp8(v0.w) << 24);
  q.y = (unsigned int)ftofp8(v1.x) | ((unsigned int)ftofp8(v1.y) << 8) |
        ((unsigned int)ftofp8(v1.z) << 16) | ((unsigned int)ftofp8(v1.w) << 24);
  *(uint2*)(featsb8 + ((size_t)b * NP + p) * NENC + tid * 8) = q;
}

// ---------------- unified LDS-tiled transpose ----------------
__device__ __forceinline__ float tfetch(int mode, int k, int n,
                                        const float* __restrict__ A,
                                        const float* __restrict__ B) {
  switch (mode) {
    case 0: return A[(size_t)k * NA + n];
    case 1: return (n < NA) ? A[(size_t)k * NA + n] : B[(size_t)k * NENC + (n - NA)];
    case 2: return A[(size_t)k * (4 * ND) + (n & 3) * ND + (n >> 2)];
    case 3: {
      int col = (n & 3) * ND + (n >> 2);
      return (k < NENC) ? A[(size_t)(NE + k) * (4 * ND) + col]
                        : B[(size_t)(k - NENC) * (4 * ND) + col];
    }
    case 4: return (n < NV) ? A[(size_t)k * NV + n] : 0.0f;
    default: return (n < NA) ? A[(size_t)k * ND + n] : B[(size_t)k * ND + (n - NA)];
  }
}

__global__ __launch_bounds__(256) void kTrans(const float* __restrict__ A,
                                              const float* __restrict__ B,
                                              u16* __restrict__ dst,
                                              int K, int N, int mode) {
  __shared__ u16 T[32][136];
  int n0 = blockIdx.x * 32, k0 = blockIdx.y * 128;
  int tid = threadIdx.x;
  int c = tid & 31, kr = tid >> 5;
#pragma unroll
  for (int pass = 0; pass < 16; ++pass) {
    int kl = pass * 8 + kr;
    T[c][kl] = f2b(tfetch(mode, k0 + kl, n0 + c, A, B));
  }
  __syncthreads();
  int row = tid >> 3, seg = tid & 7;
  u16x8 v0, v1;
#pragma unroll
  for (int j = 0; j < 8; ++j) { v0[j] = T[row][seg * 16 + j]; v1[j] = T[row][seg * 16 + 8 + j]; }
  *(u16x8*)&dst[(size_t)(n0 + row) * K + k0 + seg * 16] = v0;
  *(u16x8*)&dst[(size_t)(n0 + row) * K + k0 + seg * 16 + 8] = v1;
}

// ---------------- embA gather ----------------
__global__ void kEmbA(const float* __restrict__ emb, const int* __restrict__ captions,
                      const int* __restrict__ order, u16* __restrict__ embA) {
  int t = blockIdx.x, b = blockIdx.y;
  int tok = captions[(size_t)order[b] * NL + t];
  int i = threadIdx.x * 2;
  float2 v = *(const float2*)(emb + (size_t)tok * NE + i);
  unsigned int w0 = (unsigned int)f2b(v.x) | ((unsigned int)f2b(v.y) << 16);
  *(unsigned int*)(embA + ((size_t)t * NB + b) * NE + i) = w0;
}

// ---------------- embAll = embA @ WihTopT ----------------
__global__ __launch_bounds__(256) void kEmbGemm(const u16* __restrict__ A,
                                                const u16* __restrict__ BT,
                                                u16* __restrict__ D) {
  int w = threadIdx.x >> 6, lane = threadIdx.x & 63;
  int lr = lane & 15, lg = lane >> 4;
  int mb = blockIdx.y * 128 + w * 32;
  int nb = blockIdx.x * 64;
  f32x4 acc[2][4] = {};
  const u16* a0 = A + (size_t)(mb + lr) * NE + lg * 8;
  const u16* a1 = a0 + 16 * NE;
  const u16* b0 = BT + (size_t)(nb + lr) * NE + lg * 8;
  for (int k0 = 0; k0 < NE; k0 += 32) {
    bf16x8 af0 = *(const bf16x8*)(a0 + k0);
    bf16x8 af1 = *(const bf16x8*)(a1 + k0);
#pragma unroll
    for (int nt = 0; nt < 4; ++nt) {
      bf16x8 bf = *(const bf16x8*)(b0 + (size_t)nt * 16 * NE + k0);
      acc[0][nt] = MFMA16(af0, bf, acc[0][nt], 0, 0, 0);
      acc[1][nt] = MFMA16(af1, bf, acc[1][nt], 0, 0, 0);
    }
  }
#pragma unroll
  for (int mt = 0; mt < 2; ++mt)
#pragma unroll
    for (int nt = 0; nt < 4; ++nt)
#pragma unroll
      for (int j = 0; j < 4; ++j) {
        int row = mb + mt * 16 + lg * 4 + j;
        int col = nb + nt * 16 + lr;
        D[(size_t)row * NENC + col] = f2b(acc[mt][nt][j]);
      }
}

// ---------------- eo = mean over P ----------------
__global__ void kEo(const u16* __restrict__ featsb, u16* __restrict__ eob) {
  int e = blockIdx.x * 256 + threadIdx.x;
  int b = blockIdx.y;
  const u16* f = featsb + (size_t)b * NP * NENC + e;
  float s = 0.0f;
  for (int p = 0; p < NP; ++p) s += b2f(f[(size_t)p * NENC]);
  eob[(size_t)b * NENC + e] = f2b(s * (1.0f / NP));
}

// ---------------- h0/c0 via MFMA ----------------
__global__ __launch_bounds__(64) void kHC0(const u16* __restrict__ eob,
                                           const u16* __restrict__ BT,
                                           const float* __restrict__ b_h0,
                                           const float* __restrict__ b_c0,
                                           u16* __restrict__ hb, u16* __restrict__ xh0,
                                           float* __restrict__ c) {
  int lane = threadIdx.x;
  int lr = lane & 15, lg = lane >> 4;
  int mb = blockIdx.y * 32, nb = blockIdx.x * 32;
  f32x4 acc[2][2] = {};
  const u16* a0 = eob + (size_t)(mb + lr) * NENC + lg * 8;
  const u16* a1 = a0 + 16 * NENC;
  const u16* b0 = BT + (size_t)(nb + lr) * NENC + lg * 8;
  const u16* b1 = b0 + 16 * NENC;
#pragma unroll 4
  for (int k0 = 0; k0 < NENC; k0 += 32) {
    bf16x8 af0 = *(const bf16x8*)(a0 + k0);
    bf16x8 af1 = *(const bf16x8*)(a1 + k0);
    bf16x8 bv0 = *(const bf16x8*)(b0 + k0);
    bf16x8 bv1 = *(const bf16x8*)(b1 + k0);
    acc[0][0] = MFMA16(af0, bv0, acc[0][0], 0, 0, 0);
    acc[1][0] = MFMA16(af1, bv0, acc[1][0], 0, 0, 0);
    acc[0][1] = MFMA16(af0, bv1, acc[0][1], 0, 0, 0);
    acc[1][1] = MFMA16(af1, bv1, acc[1][1], 0, 0, 0);
  }
#pragma unroll
  for (int mt = 0; mt < 2; ++mt)
#pragma unroll
    for (int nt = 0; nt < 2; ++nt)
#pragma unroll
      for (int j = 0; j < 4; ++j) {
        int row = mb + mt * 16 + lg * 4 + j;
        int n = nb + nt * 16 + lr;
        if (n < NA) {
          u16 hv = f2b(acc[mt][nt][j] + b_h0[n]);
          hb[(size_t)row * ND + n] = hv;
          xh0[(size_t)row * KXH2 + NENC + n] = hv;
        } else {
          c[(size_t)row * ND + (n - NA)] = acc[mt][nt][j] + b_c0[n - NA];
        }
      }
}

// ---------------- enc_proj: 128x64 tiles, dbuf LDS A + register-prefetched B ----------------
__global__ __launch_bounds__(256) void kEncProj(const u16* __restrict__ A,
                                                const u16* __restrict__ BT,
                                                const float* __restrict__ bias,
                                                u16* __restrict__ D) {
  __shared__ u16 As[2][128][72];
  int lin = ((int)blockIdx.x % 8) * 196 + (int)blockIdx.x / 8;  // 1568 = 8*196
  int mt = lin >> 3, ntile = lin & 7;
  int mb = mt * 128, nb = ntile * 64;
  int tid = threadIdx.x;
  int w = tid >> 6, lane = tid & 63;
  int lr = lane & 15, lg = lane >> 4;

  int arow[4], akp[4];
  const u16* aptr[4];
#pragma unroll
  for (int i = 0; i < 4; ++i) {
    int idx = i * 256 + tid;
    arow[i] = idx >> 3;
    akp[i] = idx & 7;
    aptr[i] = A + (size_t)(mb + arow[i]) * NENC + akp[i] * 8;
  }
  u16x8 s0 = *(const u16x8*)(aptr[0]);
  u16x8 s1 = *(const u16x8*)(aptr[1]);
  u16x8 s2 = *(const u16x8*)(aptr[2]);
  u16x8 s3 = *(const u16x8*)(aptr[3]);
  *(u16x8*)&As[0][arow[0]][akp[0] * 8] = s0;
  *(u16x8*)&As[0][arow[1]][akp[1] * 8] = s1;
  *(u16x8*)&As[0][arow[2]][akp[2] * 8] = s2;
  *(u16x8*)&As[0][arow[3]][akp[3] * 8] = s3;

  f32x4 acc[2][4] = {};
  const u16* bbase = BT + (size_t)(nb + lr) * NENC + lg * 8;
  // prefetch B for k0 = 0
  bf16x8 bc[2][4];
#pragma unroll
  for (int kh = 0; kh < 2; ++kh)
#pragma unroll
    for (int nt = 0; nt < 4; ++nt)
      bc[kh][nt] = *(const bf16x8*)(bbase + (size_t)nt * 16 * NENC + kh * 32);

  int cur = 0;
  int r0 = w * 32 + lr;

  for (int k0 = 0; k0 < NENC; k0 += 64) {
    __syncthreads();
    bool more = (k0 + 64 < NENC);
    bf16x8 bn[2][4];
    if (more) {
      s0 = *(const u16x8*)(aptr[0] + k0 + 64);
      s1 = *(const u16x8*)(aptr[1] + k0 + 64);
      s2 = *(const u16x8*)(aptr[2] + k0 + 64);
      s3 = *(const u16x8*)(aptr[3] + k0 + 64);
#pragma unroll
      for (int kh = 0; kh < 2; ++kh)
#pragma unroll
        for (int nt = 0; nt < 4; ++nt)
          bn[kh][nt] = *(const bf16x8*)(bbase + (size_t)nt * 16 * NENC + k0 + 64 + kh * 32);
    }
#pragma unroll
    for (int kh = 0; kh < 2; ++kh) {
      bf16x8 af0 = *(const bf16x8*)&As[cur][r0][kh * 32 + lg * 8];
      bf16x8 af1 = *(const bf16x8*)&As[cur][r0 + 16][kh * 32 + lg * 8];
#pragma unroll
      for (int nt = 0; nt < 4; ++nt) {
        acc[0][nt] = MFMA16(af0, bc[kh][nt], acc[0][nt], 0, 0, 0);
        acc[1][nt] = MFMA16(af1, bc[kh][nt], acc[1][nt], 0, 0, 0);
      }
    }
    if (more) {
      *(u16x8*)&As[cur ^ 1][arow[0]][akp[0] * 8] = s0;
      *(u16x8*)&As[cur ^ 1][arow[1]][akp[1] * 8] = s1;
      *(u16x8*)&As[cur ^ 1][arow[2]][akp[2] * 8] = s2;
      *(u16x8*)&As[cur ^ 1][arow[3]][akp[3] * 8] = s3;
#pragma unroll
      for (int kh = 0; kh < 2; ++kh)
#pragma unroll
        for (int nt = 0; nt < 4; ++nt)
          bc[kh][nt] = bn[kh][nt];
    }
    cur ^= 1;
  }
  __syncthreads();
  u16* eps = (u16*)As;             // [128][72]
#pragma unroll
  for (int m2 = 0; m2 < 2; ++m2)
#pragma unroll
    for (int nt = 0; nt < 4; ++nt)
#pragma unroll
      for (int j = 0; j < 4; ++j) {
        int rloc = w * 32 + m2 * 16 + lg * 4 + j;
        int col = nt * 16 + lr;
        eps[rloc * 72 + col] = f2b(acc[m2][nt][j] + bias[nb + col]);
      }
  __syncthreads();
#pragma unroll
  for (int i = 0; i < 4; ++i) {
    int idx = i * 256 + tid;
    int row = idx >> 3, seg = idx & 7;
    *(u16x8*)&D[(size_t)(mb + row) * NA + nb + seg * 8] = *(u16x8*)&eps[row * 72 + seg * 8];
  }
}

// ---------------- kDecGate (R15 grid) ----------------
__global__ __launch_bounds__(64) void kDecGate(const u16* __restrict__ hb,
                                               const u16* __restrict__ BT,
                                               const float* __restrict__ b_dec,
                                               const float* __restrict__ b_beta,
                                               const int* __restrict__ nact, int t,
                                               float* __restrict__ dec_proj,
                                               float* __restrict__ gate_raw) {
  int nact_t = nact[t];
  int mb = blockIdx.y * 32;
  if (mb >= nact_t) return;
  int lane = threadIdx.x;
  int lr = lane & 15, lg = lane >> 4;
  int nb = blockIdx.x * 32;
  f32x4 acc[2][2] = {};
  const u16* a0 = hb + (size_t)(mb + lr) * ND + lg * 8;
  const u16* a1 = a0 + 16 * ND;
  const u16* b0 = BT + (size_t)(nb + lr) * ND + lg * 8;
  const u16* b1 = b0 + 16 * ND;
#pragma unroll 4
  for (int k0 = 0; k0 < ND; k0 += 32) {
    bf16x8 af0 = *(const bf16x8*)(a0 + k0);
    bf16x8 af1 = *(const bf16x8*)(a1 + k0);
    bf16x8 bv0 = *(const bf16x8*)(b0 + k0);
    bf16x8 bv1 = *(const bf16x8*)(b1 + k0);
    acc[0][0] = MFMA16(af0, bv0, acc[0][0], 0, 0, 0);
    acc[1][0] = MFMA16(af1, bv0, acc[1][0], 0, 0, 0);
    acc[0][1] = MFMA16(af0, bv1, acc[0][1], 0, 0, 0);
    acc[1][1] = MFMA16(af1, bv1, acc[1][1], 0, 0, 0);
  }
#pragma unroll
  for (int mt = 0; mt < 2; ++mt)
#pragma unroll
    for (int nt = 0; nt < 2; ++nt)
#pragma unroll
      for (int j = 0; j < 4; ++j) {
        int row = mb + mt * 16 + lg * 4 + j;
        int n = nb + nt * 16 + lr;
        if (n < NA)
          dec_proj[(size_t)row * NA + n] = acc[mt][nt][j] + b_dec[n];
        else
          gate_raw[(size_t)row * NENC + (n - NA)] = acc[mt][nt][j] + b_beta[n - NA];
      }
}

// ---------------- kSAX: R15 structure, fp8 attw reads (2 cols/thread) ----------------
__global__ __launch_bounds__(512) void kSAX(const u8* __restrict__ featsb8,
                                            const u16* __restrict__ encb,
                                            const float* __restrict__ dec_proj,
                                            const float* __restrict__ gate_raw,
                                            const float* __restrict__ w_full,
                                            const float* __restrict__ b_full,
                                            const int* __restrict__ nact, int t,
                                            u16* __restrict__ xh_w,
                                            float* __restrict__ out_alph) {
  int b = blockIdx.x, r = blockIdx.y, tid = threadIdx.x;
  if (b >= nact[t]) return;
  __shared__ float s_dp[NA], s_wf[NA], s_al[NP + 12], red[16];
  if (tid < NA) { s_dp[tid] = dec_proj[(size_t)b * NA + tid]; s_wf[tid] = w_full[tid]; }
  __syncthreads();
  int wave = tid >> 6, lane = tid & 63;
  float bf_ = b_full[0];
  for (int p = wave; p < NP; p += 8) {
    const u16* ep = encb + ((size_t)b * NP + p) * NA + lane * 8;
    u16x8 v = *(const u16x8*)ep;
    float acc = 0.0f;
#pragma unroll
    for (int j = 0; j < 8; ++j) {
      int a = lane * 8 + j;
      float vv = b2f(v[j]) + s_dp[a];
      acc += fmaxf(vv, 0.0f) * s_wf[a];
    }
#pragma unroll
    for (int off = 32; off; off >>= 1) acc += __shfl_down(acc, off);
    if (lane == 0) s_al[p] = acc + bf_;
  }
  __syncthreads();
  float mx = (tid < NP) ? s_al[tid] : -3.4e38f;
#pragma unroll
  for (int off = 32; off; off >>= 1) mx = fmaxf(mx, __shfl_down(mx, off));
  if (lane == 0) red[wave] = mx;
  __syncthreads();
  if (tid == 0) {
    float m = red[0];
    for (int i = 1; i < 8; ++i) m = fmaxf(m, red[i]);
    red[0] = m;
  }
  __syncthreads();
  float m2v = red[0];
  float e = 0.0f;
  if (tid < NP) { e = __expf(s_al[tid] - m2v); s_al[tid] = e; }
#pragma unroll
  for (int off = 32; off; off >>= 1) e += __shfl_down(e, off);
  if (lane == 0) red[8 + wave] = e;
  __syncthreads();
  if (tid == 0) {
    float s = 0.0f;
    for (int i = 0; i < 8; ++i) s += red[8 + i];
    red[8] = 1.0f / s;
  }
  __syncthreads();
  float inv = red[8];
  if (tid < NP) {
    float al = s_al[tid] * inv;
    s_al[tid] = al;
    if (r == 0) out_alph[((size_t)b * NT + t) * NP + tid] = al;
  }
  __syncthreads();
  int e0 = r * 1024 + tid * 2;
  float ac0 = 0.0f, ac1 = 0.0f;
  const u8* fb = featsb8 + (size_t)b * NP * NENC + e0;
#pragma unroll 4
  for (int p = 0; p < NP; ++p) {
    unsigned int v = (unsigned int)(*(const u16*)(fb + (size_t)p * NENC));
    float al = s_al[p];
    ac0 += al * fp8tof<0>(v);
    ac1 += al * fp8tof<1>(v);
  }
  float g0 = sigmoidf_(gate_raw[(size_t)b * NENC + e0]);
  float g1 = sigmoidf_(gate_raw[(size_t)b * NENC + e0 + 1]);
  unsigned int wo = (unsigned int)f2b(ac0 * g0) | ((unsigned int)f2b(ac1 * g1) << 16);
  *(unsigned int*)(xh_w + (size_t)b * KXH2 + e0) = wo;
}

// ---------------- kGatesLstm (R15 grid) ----------------
__global__ __launch_bounds__(1024) void kGatesLstm(const u16* __restrict__ xh_r,
                                                   const u16* __restrict__ WifgoT2,
                                                   const u16* __restrict__ embAll,
                                                   const float* __restrict__ b_ih,
                                                   const float* __restrict__ b_hh,
                                                   const int* __restrict__ nact, int t,
                                                   float* __restrict__ cst,
                                                   u16* __restrict__ hb,
                                                   u16* __restrict__ hnewAll_t,
                                                   u16* __restrict__ xh_w) {
  __shared__ float smem[8 * 32 * 33];
  int nact_t = nact[t];
  int tid = threadIdx.x;
  int w = tid >> 6, lane = tid & 63;
  int lr = lane & 15, lg = lane >> 4;
  int rt = blockIdx.x & 3, ct = blockIdx.x >> 2;
  int mb = rt * 32, nb = ct * 32;
  int kq = w >> 1, mh = w & 1;
  if (mb < nact_t) {
    f32x4 acc0 = {}, acc1 = {};
    const u16* pa = xh_r + (size_t)(mb + mh * 16 + lr) * KXH2 + kq * 320 + lg * 8;
    const u16* pb0 = WifgoT2 + (size_t)(nb + lr) * KXH2 + kq * 320 + lg * 8;
    const u16* pb1 = pb0 + (size_t)16 * KXH2;
#pragma unroll
    for (int k0 = 0; k0 < 320; k0 += 32) {
      bf16x8 af = *(const bf16x8*)(pa + k0);
      bf16x8 bv0 = *(const bf16x8*)(pb0 + k0);
      bf16x8 bv1 = *(const bf16x8*)(pb1 + k0);
      acc0 = MFMA16(af, bv0, acc0, 0, 0, 0);
      acc1 = MFMA16(af, bv1, acc1, 0, 0, 0);
    }
#pragma unroll
    for (int j = 0; j < 4; ++j) {
      int rr = kq * 32 + mh * 16 + lg * 4 + j;
      smem[rr * 33 + lr] = acc0[j];
      smem[rr * 33 + 16 + lr] = acc1[j];
    }
  }
  __syncthreads();
  if (tid < 256) {
    int row = tid >> 3, dl = tid & 7;
    int grow = mb + row;
    int d = ct * 8 + dl;
    size_t off = (size_t)grow * ND + d;
    if (grow < nact_t) {
      float g4[4];
#pragma unroll
      for (int g = 0; g < 4; ++g) {
        int col = dl * 4 + g;
        float s = 0.0f;
#pragma unroll
        for (int q = 0; q < 8; ++q) s += smem[(q * 32 + row) * 33 + col];
        s += b2f(embAll[((size_t)t * NB + grow) * NENC + nb + col]);
        g4[g] = s;
      }
      float gi = g4[0] + b_ih[d] + b_hh[d];
      float gf = g4[1] + b_ih[ND + d] + b_hh[ND + d];
      float gg = g4[2] + b_ih[2 * ND + d] + b_hh[2 * ND + d];
      float go = g4[3] + b_ih[3 * ND + d] + b_hh[3 * ND + d];
      float cn = sigmoidf_(gf) * cst[off] + sigmoidf_(gi) * tanhf(gg);
      float hn = sigmoidf_(go) * tanhf(cn);
      u16 hv = f2b(hn);
      cst[off] = cn;
      hb[off] = hv;
      hnewAll_t[off] = hv;
      xh_w[(size_t)grow * KXH2 + NENC + d] = hv;
    } else {
      xh_w[(size_t)grow * KXH2 + NENC + d] = hb[off];
    }
  }
}

// ---------------- preds GEMM: t-paired blocks, XCD-chunked, reg-prefetched A/B ----------------
__global__ __launch_bounds__(256) void kPredsAll6(const u16* __restrict__ hnewAll,
                                                  const u16* __restrict__ BT,
                                                  const float* __restrict__ b_fc,
                                                  const int* __restrict__ nact,
                                                  float* __restrict__ out_pred) {
  __shared__ float ts[128][68];
  int lin = ((int)blockIdx.x & 7) * 520 + ((int)blockIdx.x >> 3);
  if (lin >= 158 * 26) return;
  int nbi = lin / 26;
  int tp = lin - nbi * 26;
  int t0 = tp * 2;
  int t1 = t0 + 1;
  bool has1 = (t1 < NT);
  int nb = nbi * 64;
  int nact0 = nact[t0];
  int nact1 = has1 ? nact[t1] : 0;
  int w = threadIdx.x >> 6, lane = threadIdx.x & 63;
  int lr = lane & 15, lg = lane >> 4;
  int mb = w * 32;
  f32x4 acc0[2][4] = {};
  f32x4 acc1[2][4] = {};
  bool do1 = has1 && (mb < nact1);
  if (mb < nact0) {
    const u16* a0 = hnewAll + (size_t)t0 * NB * ND + (size_t)(mb + lr) * ND + lg * 8;
    const u16* a1 = a0 + 16 * ND;
    const u16* a0b = a0 + (size_t)NB * ND;
    const u16* a1b = a1 + (size_t)NB * ND;
    const u16* b0 = BT + (size_t)(nb + lr) * ND + lg * 8;
    // prefetch k0 = 0
    bf16x8 bcur[4], acur[4];
#pragma unroll
    for (int nt = 0; nt < 4; ++nt) bcur[nt] = *(const bf16x8*)(b0 + (size_t)nt * 16 * ND);
    acur[0] = *(const bf16x8*)(a0);
    acur[1] = *(const bf16x8*)(a1);
    acur[2] = do1 ? *(const bf16x8*)(a0b) : bf16x8{};
    acur[3] = do1 ? *(const bf16x8*)(a1b) : bf16x8{};
    for (int k0 = 0; k0 < ND; k0 += 32) {
      bool more = (k0 + 32 < ND);
      bf16x8 bnext[4], anext[4];
      if (more) {
#pragma unroll
        for (int nt = 0; nt < 4; ++nt)
          bnext[nt] = *(const bf16x8*)(b0 + (size_t)nt * 16 * ND + k0 + 32);
        anext[0] = *(const bf16x8*)(a0 + k0 + 32);
        anext[1] = *(const bf16x8*)(a1 + k0 + 32);
        if (do1) {
          anext[2] = *(const bf16x8*)(a0b + k0 + 32);
          anext[3] = *(const bf16x8*)(a1b + k0 + 32);
        }
      }
#pragma unroll
      for (int nt = 0; nt < 4; ++nt) {
        acc0[0][nt] = MFMA16(acur[0], bcur[nt], acc0[0][nt], 0, 0, 0);
        acc0[1][nt] = MFMA16(acur[1], bcur[nt], acc0[1][nt], 0, 0, 0);
      }
      if (do1) {
#pragma unroll
        for (int nt = 0; nt < 4; ++nt) {
          acc1[0][nt] = MFMA16(acur[2], bcur[nt], acc1[0][nt], 0, 0, 0);
          acc1[1][nt] = MFMA16(acur[3], bcur[nt], acc1[1][nt], 0, 0, 0);
        }
      }
      if (more) {
#pragma unroll
        for (int nt = 0; nt < 4; ++nt) bcur[nt] = bnext[nt];
        acur[0] = anext[0];
        acur[1] = anext[1];
        if (do1) { acur[2] = anext[2]; acur[3] = anext[3]; }
      }
    }
  }
  int tid = threadIdx.x;
#pragma unroll
  for (int mt = 0; mt < 2; ++mt)
#pragma unroll
    for (int nt = 0; nt < 4; ++nt)
#pragma unroll
      for (int j = 0; j < 4; ++j) {
        int row = mb + mt * 16 + lg * 4 + j;
        int gn = nb + nt * 16 + lr;
        float bias = (gn < NV) ? b_fc[gn] : 0.0f;
        ts[row][nt * 16 + lr] = acc0[mt][nt][j] + bias;
      }
  __syncthreads();
#pragma unroll
  for (int i = 0; i < 8; ++i) {
    int idx = i * 256 + tid;
    int row = idx >> 4;
    int c4 = (idx & 15) * 4;
    int gn = nb + c4;
    if (row < nact0 && gn < NV) {
      f32x4 v = *(const f32x4*)&ts[row][c4];
      *(f32x4*)&out_pred[((size_t)row * NT + t0) * NV + gn] = v;
    }
  }
  if (!has1) return;
  __syncthreads();
#pragma unroll
  for (int mt = 0; mt < 2; ++mt)
#pragma unroll
    for (int nt = 0; nt < 4; ++nt)
#pragma unroll
      for (int j = 0; j < 4; ++j) {
        int row = mb + mt * 16 + lg * 4 + j;
        int gn = nb + nt * 16 + lr;
        float bias = (gn < NV) ? b_fc[gn] : 0.0f;
        ts[row][nt * 16 + lr] = acc1[mt][nt][j] + bias;
      }
  __syncthreads();
#pragma unroll
  for (int i = 0; i < 8; ++i) {
    int idx = i * 256 + tid;
    int row = idx >> 4;
    int c4 = (idx & 15) * 4;
    int gn = nb + c4;
    if (row < nact1 && gn < NV) {
      f32x4 v = *(const f32x4*)&ts[row][c4];
      *(f32x4*)&out_pred[((size_t)row * NT + t1) * NV + gn] = v;
    }
  }
}

extern "C" void kernel_launch(void* const* d_in, const int* in_sizes, int n_in,
                              void* d_out, int out_size, void* d_ws, size_t ws_size,
                              hipStream_t stream) {
  (void)in_sizes; (void)n_in; (void)out_size; (void)ws_size;
  const float* features  = (const float*)d_in[0];
  const int*   captions  = (const int*)d_in[1];
  const int*   cap_len   = (const int*)d_in[2];
  const float* emb       = (const float*)d_in[3];
  const float* W_enc_att = (const float*)d_in[4];
  const float* b_enc_att = (const float*)d_in[5];
  const float* W_dec_att = (const float*)d_in[6];
  const float* b_dec_att = (const float*)d_in[7];
  const float* w_full    = (const float*)d_in[8];
  const float* b_full    = (const float*)d_in[9];
  const float* W_h0      = (const float*)d_in[10];
  const float* b_h0      = (const float*)d_in[11];
  const float* W_c0      = (const float*)d_in[12];
  const float* b_c0      = (const float*)d_in[13];
  const float* W_beta    = (const float*)d_in[14];
  const float* b_beta    = (const float*)d_in[15];
  const float* W_ih      = (const float*)d_in[16];
  const float* b_ih      = (const float*)d_in[17];
  const float* W_hh      = (const float*)d_in[18];
  const float* b_hh      = (const float*)d_in[19];
  const float* W_fc      = (const float*)d_in[20];
  const float* b_fc      = (const float*)d_in[21];

  float* out      = (float*)d_out;
  float* out_pred = out;
  float* out_cap  = out_pred + (size_t)NB * NT * NV;
  float* out_dlen = out_cap + (size_t)NB * NL;
  float* out_alph = out_dlen + NB;

  char* p = (char*)d_ws;
  auto alloc = [&](size_t nbytes) { void* r = (void*)p; p += (nbytes + 255) & ~(size_t)255; return r; };
  int*   order    = (int*)alloc(NB * 4);
  int*   nact     = (int*)alloc(NT * 4);
  int*   dlen_s   = (int*)alloc(NB * 4);
  u16*   eob      = (u16*)alloc((size_t)NB * NENC * 2);
  float* c        = (float*)alloc((size_t)NB * ND * 4);
  u16*   hb       = (u16*)alloc((size_t)NB * ND * 2);
  u16*   xh0      = (u16*)alloc((size_t)NB * KXH2 * 2);
  u16*   xh1      = (u16*)alloc((size_t)NB * KXH2 * 2);
  u16*   hnewAll  = (u16*)alloc((size_t)NT * NB * ND * 2);
  float* dec_proj = (float*)alloc((size_t)NB * NA * 4);
  float* gate_raw = (float*)alloc((size_t)NB * NENC * 4);
  u16*   featsb   = (u16*)alloc((size_t)NB * NP * NENC * 2);
  u8*    featsb8  = (u8*)alloc((size_t)NB * NP * NENC);
  u16*   encb     = (u16*)alloc((size_t)NB * NP * NA * 2);
  u16*   WencT    = (u16*)alloc((size_t)NA * NENC * 2);
  u16*   WdgT     = (u16*)alloc((size_t)(NA + NENC) * ND * 2);
  u16*   WihTopT  = (u16*)alloc((size_t)NENC * NE * 2);
  u16*   WifgoT2  = (u16*)alloc((size_t)NENC * KXH2 * 2);
  u16*   WfcT     = (u16*)alloc((size_t)NVPAD * ND * 2);
  u16*   WhcT     = (u16*)alloc((size_t)1024 * NENC * 2);
  u16*   embA     = (u16*)alloc((size_t)NT * NB * NE * 2);
  u16*   embAll   = (u16*)alloc((size_t)NT * NB * NENC * 2);

  kSort<<<1, NB, 0, stream>>>(cap_len, captions, order, nact, dlen_s, out_cap, out_dlen);
  kAlphaZero<<<NT, 256, 0, stream>>>(nact, out_alph);
  kPredTail<<<dim3(NB, 16), 256, 0, stream>>>(dlen_s, out_pred);
  kFeats<<<dim3(NP, NB), 256, 0, stream>>>(features, order, featsb, featsb8);
  kTrans<<<dim3(512 / 32, 2048 / 128), 256, 0, stream>>>(W_enc_att, nullptr, WencT, 2048, 512, 0);
  kTrans<<<dim3(2560 / 32, 512 / 128), 256, 0, stream>>>(W_dec_att, W_beta, WdgT, 512, 2560, 1);
  kTrans<<<dim3(2048 / 32, 512 / 128), 256, 0, stream>>>(W_ih, nullptr, WihTopT, 512, 2048, 2);
  kTrans<<<dim3(2048 / 32, 2560 / 128), 256, 0, stream>>>(W_ih, W_hh, WifgoT2, 2560, 2048, 3);
  kTrans<<<dim3(NVPAD / 32, 512 / 128), 256, 0, stream>>>(W_fc, nullptr, WfcT, 512, NVPAD, 4);
  kTrans<<<dim3(1024 / 32, 2048 / 128), 256, 0, stream>>>(W_h0, W_c0, WhcT, 2048, 1024, 5);
  kEmbA<<<dim3(NT, NB), 256, 0, stream>>>(emb, captions, order, embA);
  kEmbGemm<<<dim3(NENC / 64, NT), 256, 0, stream>>>(embA, WihTopT, embAll);
  kEo<<<dim3(NENC / 256, NB), 256, 0, stream>>>(featsb, eob);
  kHC0<<<dim3(1024 / 32, NB / 32), 64, 0, stream>>>(eob, WhcT, b_h0, b_c0, hb, xh0, c);
  kEncProj<<<1568, 256, 0, stream>>>(featsb, WencT, b_enc_att, encb);

  for (int t = 0; t < NT; ++t) {
    u16* xh_r = (t & 1) ? xh1 : xh0;
    u16* xh_w = (t & 1) ? xh0 : xh1;
    kDecGate<<<dim3((NA + NENC) / 32, 4), 64, 0, stream>>>(hb, WdgT, b_dec_att, b_beta,
                                                           nact, t, dec_proj, gate_raw);
    kSAX<<<dim3(NB, 2), 512, 0, stream>>>(featsb8, encb, dec_proj, gate_raw, w_full, b_full,
                                          nact, t, xh_r, out_alph);
    kGatesLstm<<<256, 1024, 0, stream>>>(xh_r, WifgoT2, embAll, b_ih, b_hh, nact, t,
                                         c, hb, hnewAll + (size_t)t * NB * ND, xh_w);
  }
  kPredsAll6<<<4160, 256, 0, stream>>>(hnewAll, WfcT, b_fc, nact, out_pred);
}

// Round 20
// 3743.649 us; speedup vs baseline: 1.1802x; 1.0013x over previous
//
#include <hip/hip_runtime.h>
#include <math.h>

#define NB 128
#define NP 196
#define NENC 2048
#define NE 512
#define ND 512
#define NA 512
#define NV 10000
#define NVPAD 10112
#define NL 52
#define NT 51
#define KXH2 2560   // [attw 2048 | h 512]

typedef unsigned short u16;
typedef unsigned char u8;
typedef __attribute__((ext_vector_type(8))) short bf16x8;
typedef __attribute__((ext_vector_type(8))) unsigned short u16x8;
typedef __attribute__((ext_vector_type(4))) float f32x4;

#define MFMA16 __builtin_amdgcn_mfma_f32_16x16x32_bf16

__device__ __forceinline__ float sigmoidf_(float v) { return 1.0f / (1.0f + __expf(-v)); }
__device__ __forceinline__ float b2f(u16 u) { return __uint_as_float(((unsigned int)u) << 16); }
__device__ __forceinline__ u16 f2b(float f) {
  unsigned int u = __float_as_uint(f);
  unsigned int r = (u + 0x7FFFu + ((u >> 16) & 1u)) >> 16;
  return (u16)r;
}

// ---- fp8 e4m3 (OCP) helpers; SEL compile-time constant ----
template <int SEL>
__device__ __forceinline__ float fp8tof(unsigned int data) {
#if __has_builtin(__builtin_amdgcn_cvt_f32_fp8)
  return __builtin_amdgcn_cvt_f32_fp8(data, SEL);
#else
  unsigned int b = (data >> (SEL * 8)) & 0xFFu;
  unsigned int s = (b & 0x80u) << 24;
  unsigned int em = b & 0x7Fu;
  float mag;
  if ((em >> 3) == 0) mag = (float)em * 0.001953125f;
  else mag = __uint_as_float((((em >> 3) + 120) << 23) | ((em & 7u) << 20));
  return __uint_as_float(s | __float_as_uint(mag));
#endif
}
__device__ __forceinline__ u8 ftofp8(float f) {
  unsigned int u = __float_as_uint(f);
  unsigned int s = (u >> 24) & 0x80u;
  float af = fabsf(f);
  if (af >= 448.0f) return (u8)(s | 0x7Eu);
  if (af < 0.015625f) {
    int m = (int)(af * 512.0f + 0.5f);
    if (m >= 8) return (u8)(s | 0x08u);
    return (u8)(s | (unsigned int)m);
  }
  int e = (int)((u >> 23) & 0xFF) - 127;
  unsigned int m3 = (u >> 20) & 7u;
  unsigned int rest = u & 0xFFFFFu;
  if (rest > 0x80000u || (rest == 0x80000u && (m3 & 1u))) { m3++; if (m3 == 8u) { m3 = 0u; e++; } }
  if (e > 8) return (u8)(s | 0x7Eu);
  return (u8)(s | ((unsigned int)(e + 7) << 3) | m3);
}

// ---------------- sort + nact + dlen_sorted ----------------
__global__ void kSort(const int* __restrict__ cap_len, const int* __restrict__ captions,
                      int* __restrict__ order, int* __restrict__ nact,
                      int* __restrict__ dlen_sorted,
                      float* __restrict__ out_cap, float* __restrict__ out_dlen) {
  __shared__ int lens[NB];
  __shared__ int s_dl[NB];
  int tid = threadIdx.x;
  lens[tid] = cap_len[tid];
  __syncthreads();
  int li = lens[tid];
  int r = 0;
  for (int j = 0; j < NB; ++j) {
    int lj = lens[j];
    if (lj > li || (lj == li && j < tid)) r++;
  }
  order[r] = tid;
  s_dl[r] = li - 1;
  dlen_sorted[r] = li - 1;
  out_dlen[r] = (float)(li - 1);
  for (int l = 0; l < NL; ++l)
    out_cap[(size_t)r * NL + l] = (float)captions[(size_t)tid * NL + l];
  __syncthreads();
  if (tid < NT) {
    int cnt = 0;
    for (int j = 0; j < NB; ++j) cnt += (s_dl[j] > tid) ? 1 : 0;
    nact[tid] = cnt;
  }
}

__global__ void kAlphaZero(const int* __restrict__ nact, float* __restrict__ out_alph) {
  int t = blockIdx.x;
  int n0 = nact[t];
  int cnt = (NB - n0) * NP;
  for (int i = threadIdx.x; i < cnt; i += 256) {
    int b = n0 + i / NP;
    int p = i - (i / NP) * NP;
    out_alph[((size_t)b * NT + t) * NP + p] = 0.0f;
  }
}

// ---------------- zero the per-row tail of predictions ----------------
__global__ __launch_bounds__(256) void kPredTail(const int* __restrict__ dlen_sorted,
                                                 float* __restrict__ out_pred) {
  int row = blockIdx.x;
  int d = dlen_sorted[row];
  int cnt = (NT - d) * NV;
  float* base = out_pred + (size_t)row * NT * NV + (size_t)d * NV;
  f32x4 z = {0.0f, 0.0f, 0.0f, 0.0f};
  int start = (blockIdx.y * 256 + threadIdx.x) * 4;
  int step = gridDim.y * 256 * 4;
  for (int i = start; i < cnt; i += step)
    *(f32x4*)&base[i] = z;
}

// ---------------- features gather + bf16 + fp8 ----------------
__global__ void kFeats(const float* __restrict__ features, const int* __restrict__ order,
                       u16* __restrict__ featsb, u8* __restrict__ featsb8) {
  int p = blockIdx.x, b = blockIdx.y, tid = threadIdx.x;
  const float* src = features + ((size_t)order[b] * NP + p) * NENC + tid * 8;
  float4 v0 = *(const float4*)src;
  float4 v1 = *(const float4*)(src + 4);
  u16x8 o;
  o[0] = f2b(v0.x); o[1] = f2b(v0.y); o[2] = f2b(v0.z); o[3] = f2b(v0.w);
  o[4] = f2b(v1.x); o[5] = f2b(v1.y); o[6] = f2b(v1.z); o[7] = f2b(v1.w);
  *(u16x8*)(featsb + ((size_t)b * NP + p) * NENC + tid * 8) = o;
  uint2 q;
  q.x = (unsigned int)ftofp8(v0.x) | ((unsigned int)ftofp8(v0.y) << 8) |
        ((unsigned int)ftofp8(v0.z) << 16) | ((unsigned int)ftofp8(v0.w) << 24);
  q.y = (unsigned int)ftofp8(v1.x) | ((unsigned int)ftofp8(v1.y) << 8) |
        ((unsigned int)ftofp8(v1.z) << 16) | ((unsigned int)ftofp8(v1.w) << 24);
  *(uint2*)(featsb8 + ((size_t)b * NP + p) * NENC + tid * 8) = q;
}

// ---------------- unified LDS-tiled transpose ----------------
__device__ __forceinline__ float tfetch(int mode, int k, int n,
                                        const float* __restrict__ A,
                                        const float* __restrict__ B) {
  switch (mode) {
    case 0: return A[(size_t)k * NA + n];
    case 1: return (n < NA) ? A[(size_t)k * NA + n] : B[(size_t)k * NENC + (n - NA)];
    case 2: return A[(size_t)k * (4 * ND) + (n & 3) * ND + (n >> 2)];
    case 3: {
      int col = (n & 3) * ND + (n >> 2);
      return (k < NENC) ? A[(size_t)(NE + k) * (4 * ND) + col]
                        : B[(size_t)(k - NENC) * (4 * ND) + col];
    }
    case 4: return (n < NV) ? A[(size_t)k * NV + n] : 0.0f;
    default: return (n < NA) ? A[(size_t)k * ND + n] : B[(size_t)k * ND + (n - NA)];
  }
}

__global__ __launch_bounds__(256) void kTrans(const float* __restrict__ A,
                                              const float* __restrict__ B,
                                              u16* __restrict__ dst,
                                              int K, int N, int mode) {
  __shared__ u16 T[32][136];
  int n0 = blockIdx.x * 32, k0 = blockIdx.y * 128;
  int tid = threadIdx.x;
  int c = tid & 31, kr = tid >> 5;
#pragma unroll
  for (int pass = 0; pass < 16; ++pass) {
    int kl = pass * 8 + kr;
    T[c][kl] = f2b(tfetch(mode, k0 + kl, n0 + c, A, B));
  }
  __syncthreads();
  int row = tid >> 3, seg = tid & 7;
  u16x8 v0, v1;
#pragma unroll
  for (int j = 0; j < 8; ++j) { v0[j] = T[row][seg * 16 + j]; v1[j] = T[row][seg * 16 + 8 + j]; }
  *(u16x8*)&dst[(size_t)(n0 + row) * K + k0 + seg * 16] = v0;
  *(u16x8*)&dst[(size_t)(n0 + row) * K + k0 + seg * 16 + 8] = v1;
}

// ---------------- embA gather ----------------
__global__ void kEmbA(const float* __restrict__ emb, const int* __restrict__ captions,
                      const int* __restrict__ order, u16* __restrict__ embA) {
  int t = blockIdx.x, b = blockIdx.y;
  int tok = captions[(size_t)order[b] * NL + t];
  int i = threadIdx.x * 2;
  float2 v = *(const float2*)(emb + (size_t)tok * NE + i);
  unsigned int w0 = (unsigned int)f2b(v.x) | ((unsigned int)f2b(v.y) << 16);
  *(unsigned int*)(embA + ((size_t)t * NB + b) * NE + i) = w0;
}

// ---------------- embAll = embA @ WihTopT ----------------
__global__ __launch_bounds__(256) void kEmbGemm(const u16* __restrict__ A,
                                                const u16* __restrict__ BT,
                                                u16* __restrict__ D) {
  int w = threadIdx.x >> 6, lane = threadIdx.x & 63;
  int lr = lane & 15, lg = lane >> 4;
  int mb = blockIdx.y * 128 + w * 32;
  int nb = blockIdx.x * 64;
  f32x4 acc[2][4] = {};
  const u16* a0 = A + (size_t)(mb + lr) * NE + lg * 8;
  const u16* a1 = a0 + 16 * NE;
  const u16* b0 = BT + (size_t)(nb + lr) * NE + lg * 8;
  for (int k0 = 0; k0 < NE; k0 += 32) {
    bf16x8 af0 = *(const bf16x8*)(a0 + k0);
    bf16x8 af1 = *(const bf16x8*)(a1 + k0);
#pragma unroll
    for (int nt = 0; nt < 4; ++nt) {
      bf16x8 bf = *(const bf16x8*)(b0 + (size_t)nt * 16 * NE + k0);
      acc[0][nt] = MFMA16(af0, bf, acc[0][nt], 0, 0, 0);
      acc[1][nt] = MFMA16(af1, bf, acc[1][nt], 0, 0, 0);
    }
  }
#pragma unroll
  for (int mt = 0; mt < 2; ++mt)
#pragma unroll
    for (int nt = 0; nt < 4; ++nt)
#pragma unroll
      for (int j = 0; j < 4; ++j) {
        int row = mb + mt * 16 + lg * 4 + j;
        int col = nb + nt * 16 + lr;
        D[(size_t)row * NENC + col] = f2b(acc[mt][nt][j]);
      }
}

// ---------------- eo = mean over P ----------------
__global__ void kEo(const u16* __restrict__ featsb, u16* __restrict__ eob) {
  int e = blockIdx.x * 256 + threadIdx.x;
  int b = blockIdx.y;
  const u16* f = featsb + (size_t)b * NP * NENC + e;
  float s = 0.0f;
  for (int p = 0; p < NP; ++p) s += b2f(f[(size_t)p * NENC]);
  eob[(size_t)b * NENC + e] = f2b(s * (1.0f / NP));
}

// ---------------- h0/c0 via MFMA ----------------
__global__ __launch_bounds__(64) void kHC0(const u16* __restrict__ eob,
                                           const u16* __restrict__ BT,
                                           const float* __restrict__ b_h0,
                                           const float* __restrict__ b_c0,
                                           u16* __restrict__ hb, u16* __restrict__ xh0,
                                           float* __restrict__ c) {
  int lane = threadIdx.x;
  int lr = lane & 15, lg = lane >> 4;
  int mb = blockIdx.y * 32, nb = blockIdx.x * 32;
  f32x4 acc[2][2] = {};
  const u16* a0 = eob + (size_t)(mb + lr) * NENC + lg * 8;
  const u16* a1 = a0 + 16 * NENC;
  const u16* b0 = BT + (size_t)(nb + lr) * NENC + lg * 8;
  const u16* b1 = b0 + 16 * NENC;
#pragma unroll 4
  for (int k0 = 0; k0 < NENC; k0 += 32) {
    bf16x8 af0 = *(const bf16x8*)(a0 + k0);
    bf16x8 af1 = *(const bf16x8*)(a1 + k0);
    bf16x8 bv0 = *(const bf16x8*)(b0 + k0);
    bf16x8 bv1 = *(const bf16x8*)(b1 + k0);
    acc[0][0] = MFMA16(af0, bv0, acc[0][0], 0, 0, 0);
    acc[1][0] = MFMA16(af1, bv0, acc[1][0], 0, 0, 0);
    acc[0][1] = MFMA16(af0, bv1, acc[0][1], 0, 0, 0);
    acc[1][1] = MFMA16(af1, bv1, acc[1][1], 0, 0, 0);
  }
#pragma unroll
  for (int mt = 0; mt < 2; ++mt)
#pragma unroll
    for (int nt = 0; nt < 2; ++nt)
#pragma unroll
      for (int j = 0; j < 4; ++j) {
        int row = mb + mt * 16 + lg * 4 + j;
        int n = nb + nt * 16 + lr;
        if (n < NA) {
          u16 hv = f2b(acc[mt][nt][j] + b_h0[n]);
          hb[(size_t)row * ND + n] = hv;
          xh0[(size_t)row * KXH2 + NENC + n] = hv;
        } else {
          c[(size_t)row * ND + (n - NA)] = acc[mt][nt][j] + b_c0[n - NA];
        }
      }
}

// ---------------- enc_proj: 128x64 tiles, dbuf LDS A, XCD swizzle (R18 version) ----------------
__global__ __launch_bounds__(256) void kEncProj(const u16* __restrict__ A,
                                                const u16* __restrict__ BT,
                                                const float* __restrict__ bias,
                                                u16* __restrict__ D) {
  __shared__ u16 As[2][128][72];
  int lin = ((int)blockIdx.x % 8) * 196 + (int)blockIdx.x / 8;  // 1568 = 8*196
  int mt = lin >> 3, ntile = lin & 7;
  int mb = mt * 128, nb = ntile * 64;
  int tid = threadIdx.x;
  int w = tid >> 6, lane = tid & 63;
  int lr = lane & 15, lg = lane >> 4;

  int arow[4], akp[4];
  const u16* aptr[4];
#pragma unroll
  for (int i = 0; i < 4; ++i) {
    int idx = i * 256 + tid;
    arow[i] = idx >> 3;
    akp[i] = idx & 7;
    aptr[i] = A + (size_t)(mb + arow[i]) * NENC + akp[i] * 8;
  }
  u16x8 s0 = *(const u16x8*)(aptr[0]);
  u16x8 s1 = *(const u16x8*)(aptr[1]);
  u16x8 s2 = *(const u16x8*)(aptr[2]);
  u16x8 s3 = *(const u16x8*)(aptr[3]);
  *(u16x8*)&As[0][arow[0]][akp[0] * 8] = s0;
  *(u16x8*)&As[0][arow[1]][akp[1] * 8] = s1;
  *(u16x8*)&As[0][arow[2]][akp[2] * 8] = s2;
  *(u16x8*)&As[0][arow[3]][akp[3] * 8] = s3;

  f32x4 acc[2][4] = {};
  const u16* bbase = BT + (size_t)(nb + lr) * NENC + lg * 8;
  int cur = 0;
  int r0 = w * 32 + lr;

  for (int k0 = 0; k0 < NENC; k0 += 64) {
    __syncthreads();
    bool more = (k0 + 64 < NENC);
    if (more) {
      s0 = *(const u16x8*)(aptr[0] + k0 + 64);
      s1 = *(const u16x8*)(aptr[1] + k0 + 64);
      s2 = *(const u16x8*)(aptr[2] + k0 + 64);
      s3 = *(const u16x8*)(aptr[3] + k0 + 64);
    }
#pragma unroll
    for (int kh = 0; kh < 2; ++kh) {
      bf16x8 af0 = *(const bf16x8*)&As[cur][r0][kh * 32 + lg * 8];
      bf16x8 af1 = *(const bf16x8*)&As[cur][r0 + 16][kh * 32 + lg * 8];
#pragma unroll
      for (int nt = 0; nt < 4; ++nt) {
        bf16x8 bf = *(const bf16x8*)(bbase + (size_t)nt * 16 * NENC + k0 + kh * 32);
        acc[0][nt] = MFMA16(af0, bf, acc[0][nt], 0, 0, 0);
        acc[1][nt] = MFMA16(af1, bf, acc[1][nt], 0, 0, 0);
      }
    }
    if (more) {
      *(u16x8*)&As[cur ^ 1][arow[0]][akp[0] * 8] = s0;
      *(u16x8*)&As[cur ^ 1][arow[1]][akp[1] * 8] = s1;
      *(u16x8*)&As[cur ^ 1][arow[2]][akp[2] * 8] = s2;
      *(u16x8*)&As[cur ^ 1][arow[3]][akp[3] * 8] = s3;
    }
    cur ^= 1;
  }
  __syncthreads();
  u16* eps = (u16*)As;             // [128][72]
#pragma unroll
  for (int m2 = 0; m2 < 2; ++m2)
#pragma unroll
    for (int nt = 0; nt < 4; ++nt)
#pragma unroll
      for (int j = 0; j < 4; ++j) {
        int rloc = w * 32 + m2 * 16 + lg * 4 + j;
        int col = nt * 16 + lr;
        eps[rloc * 72 + col] = f2b(acc[m2][nt][j] + bias[nb + col]);
      }
  __syncthreads();
#pragma unroll
  for (int i = 0; i < 4; ++i) {
    int idx = i * 256 + tid;
    int row = idx >> 3, seg = idx & 7;
    *(u16x8*)&D[(size_t)(mb + row) * NA + nb + seg * 8] = *(u16x8*)&eps[row * 72 + seg * 8];
  }
}

// ---------------- kDecGate (R15 grid) ----------------
__global__ __launch_bounds__(64) void kDecGate(const u16* __restrict__ hb,
                                               const u16* __restrict__ BT,
                                               const float* __restrict__ b_dec,
                                               const float* __restrict__ b_beta,
                                               const int* __restrict__ nact, int t,
                                               float* __restrict__ dec_proj,
                                               float* __restrict__ gate_raw) {
  int nact_t = nact[t];
  int mb = blockIdx.y * 32;
  if (mb >= nact_t) return;
  int lane = threadIdx.x;
  int lr = lane & 15, lg = lane >> 4;
  int nb = blockIdx.x * 32;
  f32x4 acc[2][2] = {};
  const u16* a0 = hb + (size_t)(mb + lr) * ND + lg * 8;
  const u16* a1 = a0 + 16 * ND;
  const u16* b0 = BT + (size_t)(nb + lr) * ND + lg * 8;
  const u16* b1 = b0 + 16 * ND;
#pragma unroll 4
  for (int k0 = 0; k0 < ND; k0 += 32) {
    bf16x8 af0 = *(const bf16x8*)(a0 + k0);
    bf16x8 af1 = *(const bf16x8*)(a1 + k0);
    bf16x8 bv0 = *(const bf16x8*)(b0 + k0);
    bf16x8 bv1 = *(const bf16x8*)(b1 + k0);
    acc[0][0] = MFMA16(af0, bv0, acc[0][0], 0, 0, 0);
    acc[1][0] = MFMA16(af1, bv0, acc[1][0], 0, 0, 0);
    acc[0][1] = MFMA16(af0, bv1, acc[0][1], 0, 0, 0);
    acc[1][1] = MFMA16(af1, bv1, acc[1][1], 0, 0, 0);
  }
#pragma unroll
  for (int mt = 0; mt < 2; ++mt)
#pragma unroll
    for (int nt = 0; nt < 2; ++nt)
#pragma unroll
      for (int j = 0; j < 4; ++j) {
        int row = mb + mt * 16 + lg * 4 + j;
        int n = nb + nt * 16 + lr;
        if (n < NA)
          dec_proj[(size_t)row * NA + n] = acc[mt][nt][j] + b_dec[n];
        else
          gate_raw[(size_t)row * NENC + (n - NA)] = acc[mt][nt][j] + b_beta[n - NA];
      }
}

// ---------------- kSAX: R15 structure, fp8 attw reads (2 cols/thread) ----------------
__global__ __launch_bounds__(512) void kSAX(const u8* __restrict__ featsb8,
                                            const u16* __restrict__ encb,
                                            const float* __restrict__ dec_proj,
                                            const float* __restrict__ gate_raw,
                                            const float* __restrict__ w_full,
                                            const float* __restrict__ b_full,
                                            const int* __restrict__ nact, int t,
                                            u16* __restrict__ xh_w,
                                            float* __restrict__ out_alph) {
  int b = blockIdx.x, r = blockIdx.y, tid = threadIdx.x;
  if (b >= nact[t]) return;
  __shared__ float s_dp[NA], s_wf[NA], s_al[NP + 12], red[16];
  if (tid < NA) { s_dp[tid] = dec_proj[(size_t)b * NA + tid]; s_wf[tid] = w_full[tid]; }
  __syncthreads();
  int wave = tid >> 6, lane = tid & 63;
  float bf_ = b_full[0];
  for (int p = wave; p < NP; p += 8) {
    const u16* ep = encb + ((size_t)b * NP + p) * NA + lane * 8;
    u16x8 v = *(const u16x8*)ep;
    float acc = 0.0f;
#pragma unroll
    for (int j = 0; j < 8; ++j) {
      int a = lane * 8 + j;
      float vv = b2f(v[j]) + s_dp[a];
      acc += fmaxf(vv, 0.0f) * s_wf[a];
    }
#pragma unroll
    for (int off = 32; off; off >>= 1) acc += __shfl_down(acc, off);
    if (lane == 0) s_al[p] = acc + bf_;
  }
  __syncthreads();
  float mx = (tid < NP) ? s_al[tid] : -3.4e38f;
#pragma unroll
  for (int off = 32; off; off >>= 1) mx = fmaxf(mx, __shfl_down(mx, off));
  if (lane == 0) red[wave] = mx;
  __syncthreads();
  if (tid == 0) {
    float m = red[0];
    for (int i = 1; i < 8; ++i) m = fmaxf(m, red[i]);
    red[0] = m;
  }
  __syncthreads();
  float m2v = red[0];
  float e = 0.0f;
  if (tid < NP) { e = __expf(s_al[tid] - m2v); s_al[tid] = e; }
#pragma unroll
  for (int off = 32; off; off >>= 1) e += __shfl_down(e, off);
  if (lane == 0) red[8 + wave] = e;
  __syncthreads();
  if (tid == 0) {
    float s = 0.0f;
    for (int i = 0; i < 8; ++i) s += red[8 + i];
    red[8] = 1.0f / s;
  }
  __syncthreads();
  float inv = red[8];
  if (tid < NP) {
    float al = s_al[tid] * inv;
    s_al[tid] = al;
    if (r == 0) out_alph[((size_t)b * NT + t) * NP + tid] = al;
  }
  __syncthreads();
  int e0 = r * 1024 + tid * 2;
  float ac0 = 0.0f, ac1 = 0.0f;
  const u8* fb = featsb8 + (size_t)b * NP * NENC + e0;
#pragma unroll 4
  for (int p = 0; p < NP; ++p) {
    unsigned int v = (unsigned int)(*(const u16*)(fb + (size_t)p * NENC));
    float al = s_al[p];
    ac0 += al * fp8tof<0>(v);
    ac1 += al * fp8tof<1>(v);
  }
  float g0 = sigmoidf_(gate_raw[(size_t)b * NENC + e0]);
  float g1 = sigmoidf_(gate_raw[(size_t)b * NENC + e0 + 1]);
  unsigned int wo = (unsigned int)f2b(ac0 * g0) | ((unsigned int)f2b(ac1 * g1) << 16);
  *(unsigned int*)(xh_w + (size_t)b * KXH2 + e0) = wo;
}

// ---------------- kGatesLstm (R15 grid) ----------------
__global__ __launch_bounds__(1024) void kGatesLstm(const u16* __restrict__ xh_r,
                                                   const u16* __restrict__ WifgoT2,
                                                   const u16* __restrict__ embAll,
                                                   const float* __restrict__ b_ih,
                                                   const float* __restrict__ b_hh,
                                                   const int* __restrict__ nact, int t,
                                                   float* __restrict__ cst,
                                                   u16* __restrict__ hb,
                                                   u16* __restrict__ hnewAll_t,
                                                   u16* __restrict__ xh_w) {
  __shared__ float smem[8 * 32 * 33];
  int nact_t = nact[t];
  int tid = threadIdx.x;
  int w = tid >> 6, lane = tid & 63;
  int lr = lane & 15, lg = lane >> 4;
  int rt = blockIdx.x & 3, ct = blockIdx.x >> 2;
  int mb = rt * 32, nb = ct * 32;
  int kq = w >> 1, mh = w & 1;
  if (mb < nact_t) {
    f32x4 acc0 = {}, acc1 = {};
    const u16* pa = xh_r + (size_t)(mb + mh * 16 + lr) * KXH2 + kq * 320 + lg * 8;
    const u16* pb0 = WifgoT2 + (size_t)(nb + lr) * KXH2 + kq * 320 + lg * 8;
    const u16* pb1 = pb0 + (size_t)16 * KXH2;
#pragma unroll
    for (int k0 = 0; k0 < 320; k0 += 32) {
      bf16x8 af = *(const bf16x8*)(pa + k0);
      bf16x8 bv0 = *(const bf16x8*)(pb0 + k0);
      bf16x8 bv1 = *(const bf16x8*)(pb1 + k0);
      acc0 = MFMA16(af, bv0, acc0, 0, 0, 0);
      acc1 = MFMA16(af, bv1, acc1, 0, 0, 0);
    }
#pragma unroll
    for (int j = 0; j < 4; ++j) {
      int rr = kq * 32 + mh * 16 + lg * 4 + j;
      smem[rr * 33 + lr] = acc0[j];
      smem[rr * 33 + 16 + lr] = acc1[j];
    }
  }
  __syncthreads();
  if (tid < 256) {
    int row = tid >> 3, dl = tid & 7;
    int grow = mb + row;
    int d = ct * 8 + dl;
    size_t off = (size_t)grow * ND + d;
    if (grow < nact_t) {
      float g4[4];
#pragma unroll
      for (int g = 0; g < 4; ++g) {
        int col = dl * 4 + g;
        float s = 0.0f;
#pragma unroll
        for (int q = 0; q < 8; ++q) s += smem[(q * 32 + row) * 33 + col];
        s += b2f(embAll[((size_t)t * NB + grow) * NENC + nb + col]);
        g4[g] = s;
      }
      float gi = g4[0] + b_ih[d] + b_hh[d];
      float gf = g4[1] + b_ih[ND + d] + b_hh[ND + d];
      float gg = g4[2] + b_ih[2 * ND + d] + b_hh[2 * ND + d];
      float go = g4[3] + b_ih[3 * ND + d] + b_hh[3 * ND + d];
      float cn = sigmoidf_(gf) * cst[off] + sigmoidf_(gi) * tanhf(gg);
      float hn = sigmoidf_(go) * tanhf(cn);
      u16 hv = f2b(hn);
      cst[off] = cn;
      hb[off] = hv;
      hnewAll_t[off] = hv;
      xh_w[(size_t)grow * KXH2 + NENC + d] = hv;
    } else {
      xh_w[(size_t)grow * KXH2 + NENC + d] = hb[off];
    }
  }
}

// ---------------- preds GEMM: t-paired blocks, XCD-chunked, reg-prefetched A/B ----------------
__global__ __launch_bounds__(256) void kPredsAll6(const u16* __restrict__ hnewAll,
                                                  const u16* __restrict__ BT,
                                                  const float* __restrict__ b_fc,
                                                  const int* __restrict__ nact,
                                                  float* __restrict__ out_pred) {
  __shared__ float ts[128][68];
  int lin = ((int)blockIdx.x & 7) * 520 + ((int)blockIdx.x >> 3);
  if (lin >= 158 * 26) return;
  int nbi = lin / 26;
  int tp = lin - nbi * 26;
  int t0 = tp * 2;
  int t1 = t0 + 1;
  bool has1 = (t1 < NT);
  int nb = nbi * 64;
  int nact0 = nact[t0];
  int nact1 = has1 ? nact[t1] : 0;
  int w = threadIdx.x >> 6, lane = threadIdx.x & 63;
  int lr = lane & 15, lg = lane >> 4;
  int mb = w * 32;
  f32x4 acc0[2][4] = {};
  f32x4 acc1[2][4] = {};
  bool do1 = has1 && (mb < nact1);
  if (mb < nact0) {
    const u16* a0 = hnewAll + (size_t)t0 * NB * ND + (size_t)(mb + lr) * ND + lg * 8;
    const u16* a1 = a0 + 16 * ND;
    const u16* a0b = a0 + (size_t)NB * ND;
    const u16* a1b = a1 + (size_t)NB * ND;
    const u16* b0 = BT + (size_t)(nb + lr) * ND + lg * 8;
    bf16x8 bcur[4], acur[4];
#pragma unroll
    for (int nt = 0; nt < 4; ++nt) bcur[nt] = *(const bf16x8*)(b0 + (size_t)nt * 16 * ND);
    acur[0] = *(const bf16x8*)(a0);
    acur[1] = *(const bf16x8*)(a1);
    acur[2] = do1 ? *(const bf16x8*)(a0b) : bf16x8{};
    acur[3] = do1 ? *(const bf16x8*)(a1b) : bf16x8{};
    for (int k0 = 0; k0 < ND; k0 += 32) {
      bool more = (k0 + 32 < ND);
      bf16x8 bnext[4], anext[4];
      if (more) {
#pragma unroll
        for (int nt = 0; nt < 4; ++nt)
          bnext[nt] = *(const bf16x8*)(b0 + (size_t)nt * 16 * ND + k0 + 32);
        anext[0] = *(const bf16x8*)(a0 + k0 + 32);
        anext[1] = *(const bf16x8*)(a1 + k0 + 32);
        if (do1) {
          anext[2] = *(const bf16x8*)(a0b + k0 + 32);
          anext[3] = *(const bf16x8*)(a1b + k0 + 32);
        }
      }
#pragma unroll
      for (int nt = 0; nt < 4; ++nt) {
        acc0[0][nt] = MFMA16(acur[0], bcur[nt], acc0[0][nt], 0, 0, 0);
        acc0[1][nt] = MFMA16(acur[1], bcur[nt], acc0[1][nt], 0, 0, 0);
      }
      if (do1) {
#pragma unroll
        for (int nt = 0; nt < 4; ++nt) {
          acc1[0][nt] = MFMA16(acur[2], bcur[nt], acc1[0][nt], 0, 0, 0);
          acc1[1][nt] = MFMA16(acur[3], bcur[nt], acc1[1][nt], 0, 0, 0);
        }
      }
      if (more) {
#pragma unroll
        for (int nt = 0; nt < 4; ++nt) bcur[nt] = bnext[nt];
        acur[0] = anext[0];
        acur[1] = anext[1];
        if (do1) { acur[2] = anext[2]; acur[3] = anext[3]; }
      }
    }
  }
  int tid = threadIdx.x;
#pragma unroll
  for (int mt = 0; mt < 2; ++mt)
#pragma unroll
    for (int nt = 0; nt < 4; ++nt)
#pragma unroll
      for (int j = 0; j < 4; ++j) {
        int row = mb + mt * 16 + lg * 4 + j;
        int gn = nb + nt * 16 + lr;
        float bias = (gn < NV) ? b_fc[gn] : 0.0f;
        ts[row][nt * 16 + lr] = acc0[mt][nt][j] + bias;
      }
  __syncthreads();
#pragma unroll
  for (int i = 0; i < 8; ++i) {
    int idx = i * 256 + tid;
    int row = idx >> 4;
    int c4 = (idx & 15) * 4;
    int gn = nb + c4;
    if (row < nact0 && gn < NV) {
      f32x4 v = *(const f32x4*)&ts[row][c4];
      *(f32x4*)&out_pred[((size_t)row * NT + t0) * NV + gn] = v;
    }
  }
  if (!has1) return;
  __syncthreads();
#pragma unroll
  for (int mt = 0; mt < 2; ++mt)
#pragma unroll
    for (int nt = 0; nt < 4; ++nt)
#pragma unroll
      for (int j = 0; j < 4; ++j) {
        int row = mb + mt * 16 + lg * 4 + j;
        int gn = nb + nt * 16 + lr;
        float bias = (gn < NV) ? b_fc[gn] : 0.0f;
        ts[row][nt * 16 + lr] = acc1[mt][nt][j] + bias;
      }
  __syncthreads();
#pragma unroll
  for (int i = 0; i < 8; ++i) {
    int idx = i * 256 + tid;
    int row = idx >> 4;
    int c4 = (idx & 15) * 4;
    int gn = nb + c4;
    if (row < nact1 && gn < NV) {
      f32x4 v = *(const f32x4*)&ts[row][c4];
      *(f32x4*)&out_pred[((size_t)row * NT + t1) * NV + gn] = v;
    }
  }
}

extern "C" void kernel_launch(void* const* d_in, const int* in_sizes, int n_in,
                              void* d_out, int out_size, void* d_ws, size_t ws_size,
                              hipStream_t stream) {
  (void)in_sizes; (void)n_in; (void)out_size; (void)ws_size;
  const float* features  = (const float*)d_in[0];
  const int*   captions  = (const int*)d_in[1];
  const int*   cap_len   = (const int*)d_in[2];
  const float* emb       = (const float*)d_in[3];
  const float* W_enc_att = (const float*)d_in[4];
  const float* b_enc_att = (const float*)d_in[5];
  const float* W_dec_att = (const float*)d_in[6];
  const float* b_dec_att = (const float*)d_in[7];
  const float* w_full    = (const float*)d_in[8];
  const float* b_full    = (const float*)d_in[9];
  const float* W_h0      = (const float*)d_in[10];
  const float* b_h0      = (const float*)d_in[11];
  const float* W_c0      = (const float*)d_in[12];
  const float* b_c0      = (const float*)d_in[13];
  const float* W_beta    = (const float*)d_in[14];
  const float* b_beta    = (const float*)d_in[15];
  const float* W_ih      = (const float*)d_in[16];
  const float* b_ih      = (const float*)d_in[17];
  const float* W_hh      = (const float*)d_in[18];
  const float* b_hh      = (const float*)d_in[19];
  const float* W_fc      = (const float*)d_in[20];
  const float* b_fc      = (const float*)d_in[21];

  float* out      = (float*)d_out;
  float* out_pred = out;
  float* out_cap  = out_pred + (size_t)NB * NT * NV;
  float* out_dlen = out_cap + (size_t)NB * NL;
  float* out_alph = out_dlen + NB;

  char* p = (char*)d_ws;
  auto alloc = [&](size_t nbytes) { void* r = (void*)p; p += (nbytes + 255) & ~(size_t)255; return r; };
  int*   order    = (int*)alloc(NB * 4);
  int*   nact     = (int*)alloc(NT * 4);
  int*   dlen_s   = (int*)alloc(NB * 4);
  u16*   eob      = (u16*)alloc((size_t)NB * NENC * 2);
  float* c        = (float*)alloc((size_t)NB * ND * 4);
  u16*   hb       = (u16*)alloc((size_t)NB * ND * 2);
  u16*   xh0      = (u16*)alloc((size_t)NB * KXH2 * 2);
  u16*   xh1      = (u16*)alloc((size_t)NB * KXH2 * 2);
  u16*   hnewAll  = (u16*)alloc((size_t)NT * NB * ND * 2);
  float* dec_proj = (float*)alloc((size_t)NB * NA * 4);
  float* gate_raw = (float*)alloc((size_t)NB * NENC * 4);
  u16*   featsb   = (u16*)alloc((size_t)NB * NP * NENC * 2);
  u8*    featsb8  = (u8*)alloc((size_t)NB * NP * NENC);
  u16*   encb     = (u16*)alloc((size_t)NB * NP * NA * 2);
  u16*   WencT    = (u16*)alloc((size_t)NA * NENC * 2);
  u16*   WdgT     = (u16*)alloc((size_t)(NA + NENC) * ND * 2);
  u16*   WihTopT  = (u16*)alloc((size_t)NENC * NE * 2);
  u16*   WifgoT2  = (u16*)alloc((size_t)NENC * KXH2 * 2);
  u16*   WfcT     = (u16*)alloc((size_t)NVPAD * ND * 2);
  u16*   WhcT     = (u16*)alloc((size_t)1024 * NENC * 2);
  u16*   embA     = (u16*)alloc((size_t)NT * NB * NE * 2);
  u16*   embAll   = (u16*)alloc((size_t)NT * NB * NENC * 2);

  kSort<<<1, NB, 0, stream>>>(cap_len, captions, order, nact, dlen_s, out_cap, out_dlen);
  kAlphaZero<<<NT, 256, 0, stream>>>(nact, out_alph);
  kPredTail<<<dim3(NB, 16), 256, 0, stream>>>(dlen_s, out_pred);
  kFeats<<<dim3(NP, NB), 256, 0, stream>>>(features, order, featsb, featsb8);
  kTrans<<<dim3(512 / 32, 2048 / 128), 256, 0, stream>>>(W_enc_att, nullptr, WencT, 2048, 512, 0);
  kTrans<<<dim3(2560 / 32, 512 / 128), 256, 0, stream>>>(W_dec_att, W_beta, WdgT, 512, 2560, 1);
  kTrans<<<dim3(2048 / 32, 512 / 128), 256, 0, stream>>>(W_ih, nullptr, WihTopT, 512, 2048, 2);
  kTrans<<<dim3(2048 / 32, 2560 / 128), 256, 0, stream>>>(W_ih, W_hh, WifgoT2, 2560, 2048, 3);
  kTrans<<<dim3(NVPAD / 32, 512 / 128), 256, 0, stream>>>(W_fc, nullptr, WfcT, 512, NVPAD, 4);
  kTrans<<<dim3(1024 / 32, 2048 / 128), 256, 0, stream>>>(W_h0, W_c0, WhcT, 2048, 1024, 5);
  kEmbA<<<dim3(NT, NB), 256, 0, stream>>>(emb, captions, order, embA);
  kEmbGemm<<<dim3(NENC / 64, NT), 256, 0, stream>>>(embA, WihTopT, embAll);
  kEo<<<dim3(NENC / 256, NB), 256, 0, stream>>>(featsb, eob);
  kHC0<<<dim3(1024 / 32, NB / 32), 64, 0, stream>>>(eob, WhcT, b_h0, b_c0, hb, xh0, c);
  kEncProj<<<1568, 256, 0, stream>>>(featsb, WencT, b_enc_att, encb);

  for (int t = 0; t < NT; ++t) {
    u16* xh_r = (t & 1) ? xh1 : xh0;
    u16* xh_w = (t & 1) ? xh0 : xh1;
    kDecGate<<<dim3((NA + NENC) / 32, 4), 64, 0, stream>>>(hb, WdgT, b_dec_att, b_beta,
                                                           nact, t, dec_proj, gate_raw);
    kSAX<<<dim3(NB, 2), 512, 0, stream>>>(featsb8, encb, dec_proj, gate_raw, w_full, b_full,
                                          nact, t, xh_r, out_alph);
    kGatesLstm<<<256, 1024, 0, stream>>>(xh_r, WifgoT2, embAll, b_ih, b_hh, nact, t,
                                         c, hb, hnewAll + (size_t)t * NB * ND, xh_w);
  }
  kPredsAll6<<<4160, 256, 0, stream>>>(hnewAll, WfcT, b_fc, nact, out_pred);
}